// Round 8
// baseline (2835.579 us; speedup 1.0000x reference)
//
#include <hip/hip_runtime.h>
#include <hip/hip_bf16.h>
#include <stdint.h>

// ---------------------------------------------------------------------------
// RNN_79164837199890: 2-layer LSTM (B=128,T=512,H=128) + policy/value heads.
// R8: persistent mega-kernel. 256 WGs x 1024 thr, all co-resident (1/CU by
// LDS). WGs 0-31: R7 merged fp8-MX scan (+C-in gate-bias injection trim).
// WGs 32-255: workers — phase 1 z0x GEMM (tickets, ascending t, agent-scope
// z stores + zdone[t] release); phase 2 heads slices (wait done[t], 2-chunk
// online-softmax to fit 128 VGPR). Scan polls zdone with pipelined probe;
// publishes done[t] after each h1(t) (R2-proven atomic pattern, R4-proven
// cheap vmcnt drain).
// ---------------------------------------------------------------------------

typedef short v8s __attribute__((ext_vector_type(8)));   // 8 x bf16 fragment
typedef float v4f __attribute__((ext_vector_type(4)));   // MFMA accumulator
typedef int   v8i __attribute__((ext_vector_type(8)));   // 32 x fp8 fragment

#define MFMA_B16(a,b,c) __builtin_amdgcn_mfma_f32_16x16x32_bf16((a),(b),(c),0,0,0)
#define MFMA_MX(a,b,c) \
  __builtin_amdgcn_mfma_scale_f32_16x16x128_f8f6f4((a),(b),(c),0,0,0,0x7F7F7F7F,0,0x7F7F7F7F)

#define NT     512
#define FIN    361
#define KP0    384
#define NPC    362
#define NPP    368
#define AG __HIP_MEMORY_SCOPE_AGENT

// workspace offsets (bytes)
#define OFF_Z     ((size_t)0)          // 65536*512*2 = 67108864 (z0x, gate-packed)
#define OFF_H1    ((size_t)83886080)   // 65536*128*2 = 16777216
#define OFF_W0XT  ((size_t)100663296)  // 512*384*2 = 393216
#define OFF_WPT   ((size_t)101187584)  // 368*128*2 = 94208
#define OFF_B0P   ((size_t)101281792)  // 512*4
#define OFF_BPP   ((size_t)101285888)  // 368*4
#define OFF_ACC   ((size_t)101287936)  // 4 floats
#define OFF_ZDONE ((size_t)101288000)  // 512 ints
#define OFF_DONE  ((size_t)101290048)  // 512 ints
#define OFF_TK    ((size_t)101292096)  // 2 ints (+pad)

static __device__ __forceinline__ short f2b(float f) {
  __hip_bfloat16 h = __float2bfloat16(f);
  union { __hip_bfloat16 h; short s; } cv; cv.h = h; return cv.s;
}
static __device__ __forceinline__ float b2f(unsigned int lo16) {
  union { unsigned u; float f; } cv; cv.u = lo16 << 16; return cv.f;
}
static __device__ __forceinline__ float u2f(unsigned int bits) {
  union { unsigned u; float f; } cv; cv.u = bits; return cv.f;
}
// f32 -> OCP e4m3fn with RNE (one-time weight packs)
static __device__ __forceinline__ unsigned f2e4m3(float f) {
  union { float f; unsigned u; } cv; cv.f = f;
  unsigned s = (cv.u >> 31) << 7;
  float a = fabsf(f);
  a = fminf(a, 448.f);
  unsigned code;
  if (a >= 0.015625f) {
    union { float f; unsigned u; } m; m.f = a;
    unsigned u = m.u + 0x7FFFF + ((m.u >> 20) & 1);
    code = (u >> 20) - 960;
    if (code > 126u) code = 126u;
  } else {
    code = (unsigned)rintf(a * 512.f);
  }
  return s | code;
}
static __device__ __forceinline__ unsigned f2e4m3_fast(float f) {
#if __has_builtin(__builtin_amdgcn_cvt_pk_fp8_f32)
  return (unsigned)__builtin_amdgcn_cvt_pk_fp8_f32(f, f, 0, false) & 0xffu;
#else
  return f2e4m3(f);
#endif
}

static __device__ __forceinline__ void sync_lds() {
  __builtin_amdgcn_sched_barrier(0);
  asm volatile("s_waitcnt lgkmcnt(0)" ::: "memory");
  __builtin_amdgcn_s_barrier();
  __builtin_amdgcn_sched_barrier(0);
}
static __device__ __forceinline__ void sync_vm() {
  __builtin_amdgcn_sched_barrier(0);
  asm volatile("s_waitcnt vmcnt(0) lgkmcnt(0)" ::: "memory");
  __builtin_amdgcn_s_barrier();
  __builtin_amdgcn_sched_barrier(0);
}

// --------------------------------------------------------------------------
// K0: weight conversion + flag zeroing.
// --------------------------------------------------------------------------
__global__ __launch_bounds__(256) void k_conv_weights(
    const float* __restrict__ W0, const float* __restrict__ b0,
    const float* __restrict__ Wp, const float* __restrict__ bp,
    char* __restrict__ ws) {
  int idx = blockIdx.x * 256 + threadIdx.x;
  __hip_bfloat16* W0xT = (__hip_bfloat16*)(ws + OFF_W0XT);
  __hip_bfloat16* WpT  = (__hip_bfloat16*)(ws + OFF_WPT);
  float* b0p = (float*)(ws + OFF_B0P);
  float* bpp = (float*)(ws + OFF_BPP);
  float* acc = (float*)(ws + OFF_ACC);
  int* zdone = (int*)(ws + OFF_ZDONE);
  int* done  = (int*)(ws + OFF_DONE);
  int* tk    = (int*)(ws + OFF_TK);

  if (idx < 196608) {                       // W0xT [512 cols'][384 k]
    int np = idx / 384, k = idx - np * 384;
    int n = (np >> 2) + 128 * (np & 3);
    float v = (k < FIN) ? W0[(size_t)k * 512 + n] : 0.f;
    W0xT[idx] = __float2bfloat16(v);
    return;
  }
  idx -= 196608;
  if (idx < 47104) {                        // WpT [368 p][128 k]
    int p = idx >> 7, k = idx & 127;
    WpT[idx] = __float2bfloat16(p < NPC ? Wp[(size_t)k * NPC + p] : 0.f);
    return;
  }
  idx -= 47104;
  if (idx < 512) {                          // b0p packed, +1.0 on forget gate
    int n = (idx >> 2) + 128 * (idx & 3);
    b0p[idx] = b0[n] + (((idx & 3) == 1) ? 1.0f : 0.0f);
    return;
  }
  idx -= 512;
  if (idx < NPP) { bpp[idx] = (idx < NPC) ? bp[idx] : -1e30f; return; }
  idx -= NPP;
  if (idx < 4) { acc[idx] = 0.f; return; }
  idx -= 4;
  if (idx < 512) { zdone[idx] = 0; return; }
  idx -= 512;
  if (idx < 512) { done[idx] = 0; return; }
  idx -= 512;
  if (idx < 8) { tk[idx] = 0; return; }
}

// --------------------------------------------------------------------------
// K_MEGA
// --------------------------------------------------------------------------
__global__ __launch_bounds__(1024, 1) void k_mega(
    const float* __restrict__ states, const int* __restrict__ moves,
    const float* __restrict__ values, const float* __restrict__ W0f,
    const float* __restrict__ W1f, const float* __restrict__ b1,
    const float* __restrict__ Wv, const float* __restrict__ bv,
    char* __restrict__ ws) {
  __shared__ char sm[110656];
  const int tid = threadIdx.x;
  const int l = tid & 63, wv = tid >> 6;
  const int c = l & 15, lg = l >> 4;

  __hip_bfloat16* Zb  = (__hip_bfloat16*)(ws + OFF_Z);
  unsigned short* h1u = (unsigned short*)(ws + OFF_H1);
  const __hip_bfloat16* W0xT = (const __hip_bfloat16*)(ws + OFF_W0XT);
  const __hip_bfloat16* WpT  = (const __hip_bfloat16*)(ws + OFF_WPT);
  const float* b0p = (const float*)(ws + OFF_B0P);
  const float* bpp = (const float*)(ws + OFF_BPP);
  float* accum = (float*)(ws + OFF_ACC);
  int* zdone = (int*)(ws + OFF_ZDONE);
  int* done  = (int*)(ws + OFF_DONE);
  int* tk    = (int*)(ws + OFF_TK);

  if (blockIdx.x < 32) {
    // =================== SCAN (R7 structure + trims) ===================
    const int role = wv >> 3, rw = wv & 7;
    const int B0 = blockIdx.x * 4;
    const int m_ = 16 * rw + c;
    const int row = 4 * lg;
    const int wf8 = row * 128 + (((m_ >> 3) ^ row) << 3) + (m_ & 7);

    for (int e = tid * 4; e < 8192; e += 1024 * 4) *(int*)(sm + e) = 0;

    auto AFRAG = [&](int base) -> v8i {
      union { unsigned long long q[4]; v8i v; } u;
#pragma unroll
      for (int t = 0; t < 4; t++)
        u.q[t] = *(const unsigned long long*)(
            sm + base + c * 128 + ((((lg * 4 + t) ^ c) & 15) << 3));
      return u.v;
    };

    if (role == 0) {
      // ---- L0 ----
      v8i breg[4];
#pragma unroll
      for (int g = 0; g < 4; g++) {
        int n = g * 128 + m_;
        union { unsigned long long q[4]; v8i v; } u;
#pragma unroll
        for (int t = 0; t < 4; t++) {
          unsigned long long w = 0ull;
#pragma unroll
          for (int j = 0; j < 8; j++) {
            int k = lg * 32 + t * 8 + j;
            w |= (unsigned long long)f2e4m3(W0f[(size_t)(FIN + k) * 512 + n]) << (8 * j);
          }
          u.q[t] = w;
        }
        breg[g] = u.v;
      }
      // prologue: wait for z(0..3)
      for (int q = 0; q < 4; q++)
        while (__hip_atomic_load(&zdone[q], __ATOMIC_ACQUIRE, AG) < 4)
          __builtin_amdgcn_s_sleep(8);

      auto ZLD = [&](int t) -> uint2 {
        unsigned long long v = __hip_atomic_load(
            (const unsigned long long*)Zb +
            (((size_t)t * 128 + B0 + lg) * 512 + m_ * 4) / 4,
            __ATOMIC_RELAXED, AG);
        union { unsigned long long q; uint2 u; } cv; cv.q = v; return cv.u;
      };
      uint2 zA = ZLD(0), zB = ZLD(1), zC;
      float cst = 0.f;
      v4f acc[4];
#pragma unroll
      for (int g = 0; g < 4; g++) acc[g] = (v4f){0.f, 0.f, 0.f, 0.f};
      int zseen = 4;
      const bool p0 = (tid == 0);
      __syncthreads();

      for (int s = 0; s < NT; s++) {
        int fl = 0;
        if (p0 && zseen < NT)
          fl = __hip_atomic_load(&zdone[zseen], __ATOMIC_RELAXED, AG);
        v8i av = AFRAG(((s + 1) & 1) * 2048);
        acc[0][0] = u2f(zA.x << 16);
        acc[1][0] = u2f(zA.x & 0xffff0000u);
        acc[2][0] = u2f(zA.y << 16);
        acc[3][0] = u2f(zA.y & 0xffff0000u);
#pragma unroll
        for (int g = 0; g < 4; g++) acc[g] = MFMA_MX(av, breg[g], acc[g]);
        if (s + 2 < NT) zC = ZLD(s + 2);

        float xi = acc[0][0], xf = acc[1][0], xg = acc[2][0], xo = acc[3][0];
        float ei = __expf(-xi);
        float ef = __expf(-xf);
        float eg = __expf(2.f * xg);
        float eo = __expf(-xo);
        float cn = cst * __builtin_amdgcn_rcpf(1.f + ef)
                 + (eg - 1.f) * __builtin_amdgcn_rcpf((1.f + ei) * (eg + 1.f));
        cst = cn;
        float ec = __expf(2.f * cn);
        float hv = (ec - 1.f) * __builtin_amdgcn_rcpf((1.f + eo) * (ec + 1.f));
        *(unsigned char*)(sm + (s & 1) * 2048 + wf8) = (unsigned char)f2e4m3_fast(hv);
        zA = zB; zB = zC;
        if (p0) {
          if (zseen < NT && fl >= 4) zseen++;
          int need = s + 4; if (need > NT) need = NT;
          while (zseen < need) {
            if (__hip_atomic_load(&zdone[zseen], __ATOMIC_ACQUIRE, AG) >= 4) zseen++;
            else __builtin_amdgcn_s_sleep(8);
          }
        }
        sync_lds();
      }
      sync_lds();                           // L1 tail step
    } else {
      // ---- L1 (one step behind) ----
      v8i bregH[4], bregX[4];
#pragma unroll
      for (int g = 0; g < 4; g++) {
        int n = g * 128 + m_;
        union { unsigned long long q[4]; v8i v; } uh, ux;
#pragma unroll
        for (int t = 0; t < 4; t++) {
          unsigned long long wh = 0ull, wx = 0ull;
#pragma unroll
          for (int j = 0; j < 8; j++) {
            int k = lg * 32 + t * 8 + j;
            wh |= (unsigned long long)f2e4m3(W1f[(size_t)(128 + k) * 512 + n]) << (8 * j);
            wx |= (unsigned long long)f2e4m3(W1f[(size_t)k * 512 + n]) << (8 * j);
          }
          uh.q[t] = wh; ux.q[t] = wx;
        }
        bregH[g] = uh.v; bregX[g] = ux.v;
      }
      float bq[4];
#pragma unroll
      for (int g = 0; g < 4; g++)
        bq[g] = b1[g * 128 + m_] + ((g == 1) ? 1.0f : 0.0f);
      float cst = 0.f;
      v4f acc[4];
#pragma unroll
      for (int g = 0; g < 4; g++) acc[g] = (v4f){bq[g], bq[g], bq[g], bq[g]};
      const bool pd = (tid == 512);
      __syncthreads();
      sync_lds();                           // skip s=0

      for (int s = 1; s <= NT; s++) {
        v8i ah = AFRAG(4096 + (s & 1) * 2048);
        v8i ax = AFRAG(((s + 1) & 1) * 2048);
#pragma unroll
        for (int g = 0; g < 4; g++) acc[g][0] = bq[g];
#pragma unroll
        for (int g = 0; g < 4; g++) acc[g] = MFMA_MX(ah, bregH[g], acc[g]);
#pragma unroll
        for (int g = 0; g < 4; g++) acc[g] = MFMA_MX(ax, bregX[g], acc[g]);

        float xi = acc[0][0], xf = acc[1][0], xg = acc[2][0], xo = acc[3][0];
        float ei = __expf(-xi);
        float ef = __expf(-xf);
        float eg = __expf(2.f * xg);
        float eo = __expf(-xo);
        float cn = cst * __builtin_amdgcn_rcpf(1.f + ef)
                 + (eg - 1.f) * __builtin_amdgcn_rcpf((1.f + ei) * (eg + 1.f));
        cst = cn;
        float ec = __expf(2.f * cn);
        float hv = (ec - 1.f) * __builtin_amdgcn_rcpf((1.f + eo) * (ec + 1.f));
        *(unsigned char*)(sm + 4096 + ((s + 1) & 1) * 2048 + wf8) =
            (unsigned char)f2e4m3_fast(hv);
        __hip_atomic_store(
            h1u + ((size_t)(s - 1) * 128 + B0 + lg) * 128 + m_,
            (unsigned short)f2b(hv), __ATOMIC_RELAXED, AG);
        sync_vm();                          // drain stores, then publish
        if (pd) __hip_atomic_fetch_add(&done[s - 1], 1, __ATOMIC_RELEASE, AG);
      }
    }
    return;
  }

  // ======================= WORKERS =======================
  int* tks = (int*)(sm + 110592);
  const int wm = wv;                        // wave id (valid < 4 when tid<256)

  // ---- Phase 1: z0x GEMM tickets (i -> bx=i>>2 t-tile, by=i&3 n-tile) ----
  for (;;) {
    if (tid == 0) *tks = atomicAdd(&tk[0], 1);
    __syncthreads();
    int i = *tks;
    __syncthreads();
    if (i >= 2048) break;
    const int bx = i >> 2, by = i & 3;
    const int m0 = bx * 128, n0 = by * 128;
    v4f ga[2][8];
    if (tid < 256) {
#pragma unroll
      for (int mt = 0; mt < 2; mt++)
#pragma unroll
        for (int nt = 0; nt < 8; nt++) ga[mt][nt] = (v4f){0.f, 0.f, 0.f, 0.f};
    }
    for (int ks = 0; ks < 6; ks++) {
      __syncthreads();
      if (tid < 256) {
#pragma unroll
        for (int ii = 0; ii < 4; ii++) {
          int idx = ii * 4096 + tid * 16;
          int rr = idx >> 7, colb = idx & 127;
          int r = m0 + rr;
          const float* src = states + ((size_t)(r & 127) * NT + (r >> 7)) * FIN;
          int kb = ks * 64 + (colb >> 1);
          v8s w;
#pragma unroll
          for (int u = 0; u < 8; u++) {
            int kf = kb + u;
            w[u] = f2b((kf < FIN) ? src[kf] : 0.f);
          }
          *(v8s*)(sm + rr * 128 + (colb ^ ((rr & 7) << 4))) = w;
          uint4 rbv = *(const uint4*)((const char*)W0xT +
              ((size_t)(n0 + rr) * KP0 + ks * 64) * 2 + colb);
          *(uint4*)(sm + 16384 + rr * 128 + (colb ^ ((rr & 7) << 4))) = rbv;
        }
      }
      __syncthreads();
      if (tid < 256) {
#pragma unroll
        for (int kk = 0; kk < 2; kk++) {
          int bir = kk * 64 + lg * 16;
          v8s af[2];
#pragma unroll
          for (int mt = 0; mt < 2; mt++) {
            int rr = wm * 32 + mt * 16 + c;
            af[mt] = *(v8s*)(sm + rr * 128 + (bir ^ ((rr & 7) << 4)));
          }
#pragma unroll
          for (int nt = 0; nt < 8; nt++) {
            int n = nt * 16 + c;
            v8s bf = *(v8s*)(sm + 16384 + n * 128 + (bir ^ ((n & 7) << 4)));
#pragma unroll
            for (int mt = 0; mt < 2; mt++) ga[mt][nt] = MFMA_B16(af[mt], bf, ga[mt][nt]);
          }
        }
      }
    }
    if (tid < 256) {
#pragma unroll
      for (int mt = 0; mt < 2; mt++)
#pragma unroll
        for (int nt = 0; nt < 8; nt++) {
          int colp = n0 + nt * 16 + c;
          float bs = b0p[colp];
#pragma unroll
          for (int j = 0; j < 4; j++) {
            int rp = m0 + wm * 32 + mt * 16 + lg * 4 + j;
            __hip_atomic_store((unsigned short*)Zb + (size_t)rp * 512 + colp,
                               (unsigned short)f2b(ga[mt][nt][j] + bs),
                               __ATOMIC_RELAXED, AG);
          }
        }
    }
    __syncthreads();                        // drains vmcnt
    if (tid == 0) __hip_atomic_fetch_add(&zdone[bx], 1, __ATOMIC_RELEASE, AG);
  }

  // ---- Phase 2: heads. Stage WpT once, then consume t-slices ----
  if (tid < 256) {
#pragma unroll
    for (int ii = 0; ii < 23; ii++) {
      int idx = ii * 4096 + tid * 16;
      int rr = idx >> 8, colb = idx & 255;
      uint4 v = *(const uint4*)((const char*)WpT + idx);
      *(uint4*)(sm + 16384 + rr * 256 + (colb ^ ((rr & 7) << 4))) = v;
    }
  }
  for (;;) {
    if (tid == 0) *tks = atomicAdd(&tk[1], 1);
    __syncthreads();
    int j = *tks;
    __syncthreads();
    if (j >= 1024) break;
    const int r0 = j * 64;
    const int tt = r0 >> 7;
    if (tid == 0) {
      while (__hip_atomic_load(&done[tt], __ATOMIC_ACQUIRE, AG) < 32)
        __builtin_amdgcn_s_sleep(8);
    }
    __syncthreads();
    if (tid < 256) {
#pragma unroll
      for (int ii = 0; ii < 8; ii++) {
        int idx = ii * 2048 + tid * 8;
        int rr = idx >> 8, colb = idx & 255;
        unsigned long long v = __hip_atomic_load(
            (const unsigned long long*)h1u + (size_t)r0 * 32 + (idx >> 3),
            __ATOMIC_RELAXED, AG);
        *(unsigned long long*)(sm + rr * 256 + (colb ^ ((rr & 7) << 4))) = v;
      }
    }
    __syncthreads();
    if (tid < 256) {
      float m_[4], l_[4], mlv[4], amx[4]; int aix[4];
      int mv_[4]; float val_[4];
#pragma unroll
      for (int jj = 0; jj < 4; jj++) {
        int r = r0 + wm * 16 + lg * 4 + jj;
        int t = r >> 7, b = r & 127;
        mv_[jj] = moves[(size_t)b * NT + t];
        val_[jj] = values[(size_t)b * NT + t];
        m_[jj] = -3.0e38f; l_[jj] = 0.f; mlv[jj] = 0.f;
        amx[jj] = -3.0e38f; aix[jj] = 0;
      }
#pragma unroll
      for (int ch = 0; ch < 2; ch++) {
        const int q0 = ch * 12;
        const int nq = ch ? 11 : 12;
        v4f acc[12];
#pragma unroll
        for (int q = 0; q < 12; q++) acc[q] = (v4f){0.f, 0.f, 0.f, 0.f};
#pragma unroll
        for (int kk = 0; kk < 4; kk++) {
          int bir = kk * 64 + lg * 16;
          int ar = wm * 16 + c;
          v8s a = *(v8s*)(sm + ar * 256 + (bir ^ ((ar & 7) << 4)));
          for (int q = 0; q < nq; q++) {
            int n = (q0 + q) * 16 + c;
            v8s bfr = *(v8s*)(sm + 16384 + n * 256 + (bir ^ ((n & 7) << 4)));
            acc[q] = MFMA_B16(a, bfr, acc[q]);
          }
        }
        float bqc[12];
        for (int q = 0; q < nq; q++) bqc[q] = bpp[(q0 + q) * 16 + c];
#pragma unroll
        for (int jj = 0; jj < 4; jj++) {
          float pm = -3.0e38f;
          for (int q = 0; q < nq; q++) pm = fmaxf(pm, acc[q][jj] + bqc[q]);
#pragma unroll
          for (int d = 1; d < 16; d <<= 1) pm = fmaxf(pm, __shfl_xor(pm, d, 64));
          float nm = fmaxf(m_[jj], pm);
          float sc = __expf(m_[jj] - nm);
          float ps = 0.f;
          for (int q = 0; q < nq; q++) ps += __expf((acc[q][jj] + bqc[q]) - nm);
#pragma unroll
          for (int d = 1; d < 16; d <<= 1) ps += __shfl_xor(ps, d, 64);
          l_[jj] = l_[jj] * sc + ps;
          m_[jj] = nm;
          int qm = mv_[jj] >> 4, cm = mv_[jj] & 15;
          float vvm = 0.f;
          for (int q = 0; q < nq; q++) if (q0 + q == qm) vvm = acc[q][jj] + bqc[q];
          vvm = __shfl(vvm, (l & 48) + cm, 64);
          if (qm >= q0 && qm < q0 + nq) mlv[jj] = vvm;
          for (int q = 0; q < nq; q++) {
            float v = acc[q][jj] + bqc[q];
            if (v > amx[jj]) { amx[jj] = v; aix[jj] = (q0 + q) * 16 + c; }
          }
        }
      }
      float tp = 0.f, tv = 0.f, ta = 0.f, tn = 0.f;
#pragma unroll
      for (int jj = 0; jj < 4; jj++) {
        float am = amx[jj]; int ai = aix[jj];
#pragma unroll
        for (int d = 1; d < 16; d <<= 1) {
          float ov = __shfl_xor(am, d, 64);
          int oi = __shfl_xor(ai, d, 64);
          if (ov > am || (ov == am && oi < ai)) { am = ov; ai = oi; }
        }
        float lse = m_[jj] + __logf(l_[jj]);
        float xent = lse - mlv[jj];
        float pdv = 0.f;
        int vrow = wm * 16 + lg * 4 + jj;
#pragma unroll
        for (int ii = 0; ii < 8; ii++) {
          int k = c * 8 + ii;
          short hvb = *(short*)(sm + vrow * 256 + ((k * 2) ^ ((vrow & 7) << 4)));
          pdv += b2f((unsigned short)hvb) * Wv[k];
        }
#pragma unroll
        for (int d = 1; d < 16; d <<= 1) pdv += __shfl_xor(pdv, d, 64);
        float eo = __expf(2.f * (pdv + bv[0]));
        float win = (eo - 1.f) * __builtin_amdgcn_rcpf(eo + 1.f);
        float dv = win - val_[jj];
        float msk = (val_[jj] != -9.0f) ? 1.f : 0.f;
        if (c == 0) {
          tp += msk * xent;
          tv += msk * dv * dv;
          ta += (ai == mv_[jj]) ? 1.f : 0.f;
          tn += msk;
        }
      }
      tp += __shfl_xor(tp, 16, 64); tp += __shfl_xor(tp, 32, 64);
      tv += __shfl_xor(tv, 16, 64); tv += __shfl_xor(tv, 32, 64);
      ta += __shfl_xor(ta, 16, 64); ta += __shfl_xor(ta, 32, 64);
      tn += __shfl_xor(tn, 16, 64); tn += __shfl_xor(tn, 32, 64);
      if (l == 0) {
        atomicAdd(accum + 0, tp);
        atomicAdd(accum + 1, tv);
        atomicAdd(accum + 2, ta);
        atomicAdd(accum + 3, tn);
      }
    }
    __syncthreads();
  }
}

__global__ void k_final(const float* __restrict__ accum, float* __restrict__ out) {
  if (threadIdx.x == 0) {
    float nm = accum[3];
    out[0] = accum[0] / nm;
    out[1] = accum[1] / nm;
    out[2] = accum[2] / 65536.0f;
  }
}

// --------------------------------------------------------------------------
extern "C" void kernel_launch(void* const* d_in, const int* in_sizes, int n_in,
                              void* d_out, int out_size, void* d_ws, size_t ws_size,
                              hipStream_t stream) {
  (void)in_sizes; (void)n_in; (void)out_size; (void)ws_size;
  const float* states = (const float*)d_in[0];
  const int*   moves  = (const int*)d_in[1];
  const float* values = (const float*)d_in[2];
  const float* W0 = (const float*)d_in[3];
  const float* b0 = (const float*)d_in[4];
  const float* W1 = (const float*)d_in[5];
  const float* b1 = (const float*)d_in[6];
  const float* Wp = (const float*)d_in[7];
  const float* bp = (const float*)d_in[8];
  const float* Wv = (const float*)d_in[9];
  const float* bv = (const float*)d_in[10];
  char* ws = (char*)d_ws;

  k_conv_weights<<<960, 256, 0, stream>>>(W0, b0, Wp, bp, ws);
  k_mega<<<256, 1024, 0, stream>>>(states, moves, values, W0, W1, b1, Wv, bv, ws);
  k_final<<<1, 1, 0, stream>>>((const float*)(ws + OFF_ACC), (float*)d_out);
}

// Round 9
// 1122.897 us; speedup vs baseline: 2.5252x; 2.5252x over previous
//
#include <hip/hip_runtime.h>
#include <hip/hip_bf16.h>
#include <stdint.h>

// ---------------------------------------------------------------------------
// RNN_79164837199890: 2-layer LSTM (B=128,T=512,H=128) + policy/value heads.
// R9: R7 structure (R8 persistent/polling reverted — 224 spinning WGs cost
// 250+250 MB/dispatch of HBM poll traffic and 5x'd the scan). Scan VALU trims:
//   (1) log2e/sign folded into scan weights/biases/z (exp -> bare v_exp_f32)
//   (2) z'/b1' injected via MFMA C-in (kills adds + acc re-init)
//   (3) fp8 encode via inline-asm v_cvt_pk_fp8_f32 (1 op)
//   (4) s_setprio(1) around MFMA clusters (role-split schedule => T5 applies)
// ---------------------------------------------------------------------------

typedef short v8s __attribute__((ext_vector_type(8)));   // 8 x bf16 fragment
typedef float v4f __attribute__((ext_vector_type(4)));   // MFMA accumulator
typedef int   v8i __attribute__((ext_vector_type(8)));   // 32 x fp8 fragment

#define MFMA_B16(a,b,c) __builtin_amdgcn_mfma_f32_16x16x32_bf16((a),(b),(c),0,0,0)
#define MFMA_MX(a,b,c) \
  __builtin_amdgcn_mfma_scale_f32_16x16x128_f8f6f4((a),(b),(c),0,0,0,0x7F7F7F7F,0,0x7F7F7F7F)

#define NT     512
#define FIN    361
#define KP0    384
#define NPC    362
#define NPP    368
// gate scale factors: xi,xf,xo -> -log2e (exp(-x)=2^(x')); xg -> +2log2e
#define NL2E  (-1.4426950408889634f)
#define L2E2  (2.8853900817779268f)

// workspace offsets (bytes)
#define OFF_Z    ((size_t)0)          // 65536*512*2 = 67108864 (z0x', gate-packed, scaled)
#define OFF_H1   ((size_t)83886080)   // 65536*128*2 = 16777216
#define OFF_W0XT ((size_t)100663296)  // 512*384*2 = 393216
#define OFF_WPT  ((size_t)101187584)  // 368*128*2 = 94208
#define OFF_B0P  ((size_t)101281792)  // 512*4
#define OFF_BPP  ((size_t)101285888)  // 368*4
#define OFF_ACC  ((size_t)101287936)  // 4 floats

static __device__ __forceinline__ short f2b(float f) {
  __hip_bfloat16 h = __float2bfloat16(f);
  union { __hip_bfloat16 h; short s; } cv; cv.h = h; return cv.s;
}
static __device__ __forceinline__ float b2f(unsigned int lo16) {
  union { unsigned u; float f; } cv; cv.u = lo16 << 16; return cv.f;
}
static __device__ __forceinline__ float u2f(unsigned int bits) {
  union { unsigned u; float f; } cv; cv.u = bits; return cv.f;
}
// f32 -> OCP e4m3fn with RNE (one-time weight packs)
static __device__ __forceinline__ unsigned f2e4m3(float f) {
  union { float f; unsigned u; } cv; cv.f = f;
  unsigned s = (cv.u >> 31) << 7;
  float a = fabsf(f);
  a = fminf(a, 448.f);
  unsigned code;
  if (a >= 0.015625f) {
    union { float f; unsigned u; } m; m.f = a;
    unsigned u = m.u + 0x7FFFF + ((m.u >> 20) & 1);
    code = (u >> 20) - 960;
    if (code > 126u) code = 126u;
  } else {
    code = (unsigned)rintf(a * 512.f);
  }
  return s | code;
}
// per-step fp8 encode: 1 VALU op (no builtin on gfx950 — inline asm)
static __device__ __forceinline__ unsigned cvtfp8(float f) {
  unsigned r = 0;
  asm("v_cvt_pk_fp8_f32 %0, %1, %2" : "+v"(r) : "v"(f), "v"(f));
  return r & 0xffu;
}
// bare 2^x (scale pre-folded into weights)
static __device__ __forceinline__ float exp2a(float x) {
  float r;
  asm("v_exp_f32 %0, %1" : "=v"(r) : "v"(x));
  return r;
}

// Raw barrier with LDS-only drain (global stores/loads keep floating).
static __device__ __forceinline__ void sync_lds() {
  __builtin_amdgcn_sched_barrier(0);
  asm volatile("s_waitcnt lgkmcnt(0)" ::: "memory");
  __builtin_amdgcn_s_barrier();
  __builtin_amdgcn_sched_barrier(0);
}

// --------------------------------------------------------------------------
// K0: weight conversion. Packed gate order: col' = m*4+g  <->  n = m + 128*g
// Forget +1.0 folded into b0p; gate log2e factors folded into W0xT/b0p.
// --------------------------------------------------------------------------
__global__ __launch_bounds__(256) void k_conv_weights(
    const float* __restrict__ W0, const float* __restrict__ b0,
    const float* __restrict__ Wp, const float* __restrict__ bp,
    char* __restrict__ ws) {
  int idx = blockIdx.x * 256 + threadIdx.x;
  __hip_bfloat16* W0xT = (__hip_bfloat16*)(ws + OFF_W0XT);
  __hip_bfloat16* WpT  = (__hip_bfloat16*)(ws + OFF_WPT);
  float* b0p = (float*)(ws + OFF_B0P);
  float* bpp = (float*)(ws + OFF_BPP);
  float* acc = (float*)(ws + OFF_ACC);

  if (idx < 196608) {                       // W0xT [512 cols'][384 k], scaled
    int np = idx / 384, k = idx - np * 384;
    int n = (np >> 2) + 128 * (np & 3);
    float fac = ((np & 3) == 2) ? L2E2 : NL2E;
    float v = (k < FIN) ? W0[(size_t)k * 512 + n] * fac : 0.f;
    W0xT[idx] = __float2bfloat16(v);
    return;
  }
  idx -= 196608;
  if (idx < 47104) {                        // WpT [368 p][128 k]
    int p = idx >> 7, k = idx & 127;
    WpT[idx] = __float2bfloat16(p < NPC ? Wp[(size_t)k * NPC + p] : 0.f);
    return;
  }
  idx -= 47104;
  if (idx < 512) {                          // b0p packed: (+1 forget) * fac
    int g = idx & 3;
    int n = (idx >> 2) + 128 * g;
    float fac = (g == 2) ? L2E2 : NL2E;
    b0p[idx] = (b0[n] + ((g == 1) ? 1.0f : 0.0f)) * fac;
    return;
  }
  idx -= 512;
  if (idx < NPP) { bpp[idx] = (idx < NPC) ? bp[idx] : -1e30f; return; }
  idx -= NPP;
  if (idx < 4) { acc[idx] = 0.f; return; }
}

// --------------------------------------------------------------------------
// K1: C[r, col'] = A[r,:] @ BT[col',:]^T + bias[col'],  C bf16 [65536][512]
// (B/bias pre-scaled by gate factors => C = z' directly.)
// --------------------------------------------------------------------------
template<int KTOT, bool AF32>
__global__ __launch_bounds__(256) void k_gemm(
    const void* __restrict__ Ap, const __hip_bfloat16* __restrict__ BT,
    const float* __restrict__ bias, __hip_bfloat16* __restrict__ C) {
  __shared__ char sm[65536];                 // A: 2x16KB @0, B: 2x16KB @32768
  const int tid = threadIdx.x;
  const int l = tid & 63, wm = tid >> 6;
  const int c = l & 15, lg = l >> 4;
  const int m0 = blockIdx.x * 128;
  const int n0 = blockIdx.y * 128;
  constexpr int NS = KTOT / 64;

  uint4 ra[4], rb[4];
  float fa[32];

  auto LD = [&](int ks) {
#pragma unroll
    for (int i = 0; i < 4; i++) {
      int idx = i * 4096 + tid * 16;
      int row = idx >> 7, colb = idx & 127;
      if constexpr (AF32) {
        int r = m0 + row;
        const float* src = (const float*)Ap + ((size_t)(r & 127) * NT + (r >> 7)) * FIN;
        int kb = ks * 64 + (colb >> 1);
#pragma unroll
        for (int u = 0; u < 8; u++) {
          int kf = kb + u;
          fa[i * 8 + u] = (kf < FIN) ? src[kf] : 0.f;
        }
      } else {
        ra[i] = *(const uint4*)((const char*)Ap + ((size_t)(m0 + row) * KTOT + ks * 64) * 2 + colb);
      }
      rb[i] = *(const uint4*)((const char*)BT + ((size_t)(n0 + row) * KTOT + ks * 64) * 2 + colb);
    }
  };
  auto ST = [&](int bsel) {
#pragma unroll
    for (int i = 0; i < 4; i++) {
      int idx = i * 4096 + tid * 16;
      int row = idx >> 7, colb = idx & 127;
      int sw = colb ^ ((row & 7) << 4);
      if constexpr (AF32) {
        v8s w;
#pragma unroll
        for (int u = 0; u < 8; u++) w[u] = f2b(fa[i * 8 + u]);
        *(v8s*)(sm + bsel * 16384 + row * 128 + sw) = w;
      } else {
        *(uint4*)(sm + bsel * 16384 + row * 128 + sw) = ra[i];
      }
      *(uint4*)(sm + 32768 + bsel * 16384 + row * 128 + sw) = rb[i];
    }
  };

  v4f acc[2][8];
  v4f z4 = {0.f, 0.f, 0.f, 0.f};
#pragma unroll
  for (int mt = 0; mt < 2; mt++)
#pragma unroll
    for (int nt = 0; nt < 8; nt++) acc[mt][nt] = z4;

  LD(0); ST(0);
  __syncthreads();
  for (int ks = 0; ks < NS; ks++) {
    if (ks + 1 < NS) LD(ks + 1);
    const int bsel = ks & 1;
#pragma unroll
    for (int kk = 0; kk < 2; kk++) {
      int bir = kk * 64 + lg * 16;
      v8s af[2];
#pragma unroll
      for (int mt = 0; mt < 2; mt++) {
        int row = wm * 32 + mt * 16 + c;
        af[mt] = *(v8s*)(sm + bsel * 16384 + row * 128 + (bir ^ ((row & 7) << 4)));
      }
#pragma unroll
      for (int nt = 0; nt < 8; nt++) {
        int n = nt * 16 + c;
        v8s bf = *(v8s*)(sm + 32768 + bsel * 16384 + n * 128 + (bir ^ ((n & 7) << 4)));
#pragma unroll
        for (int mt = 0; mt < 2; mt++) acc[mt][nt] = MFMA_B16(af[mt], bf, acc[mt][nt]);
      }
    }
    if (ks + 1 < NS) ST((ks + 1) & 1);
    __syncthreads();
  }

#pragma unroll
  for (int mt = 0; mt < 2; mt++)
#pragma unroll
    for (int nt = 0; nt < 8; nt++) {
      int colp = n0 + nt * 16 + c;
      float bs = bias[colp];
#pragma unroll
      for (int j = 0; j < 4; j++) {
        int row = m0 + wm * 32 + mt * 16 + lg * 4 + j;
        C[(size_t)row * 512 + colp] = __float2bfloat16(acc[mt][nt][j] + bs);
      }
    }
}

// --------------------------------------------------------------------------
// K2: merged 2-layer scan, MX K=128 fp8, VALU-trimmed. 32 WGs x 16 waves.
// role = wv>>3 (0: L0; 1: L1 one step behind). lane: m=16rw+c, batch B0+lg
// (M-row 4lg), 1 cell/lane. LDS: h0 fp8 dbuf @0, h1 fp8 dbuf @4096.
// Weights pre-scaled by gate log2e factors; z'/b1' via MFMA C-in.
// --------------------------------------------------------------------------
__global__ __launch_bounds__(1024, 4) void k_scan12(
    const __hip_bfloat16* __restrict__ Z, const float* __restrict__ W0f,
    const float* __restrict__ W1f, const float* __restrict__ b1,
    __hip_bfloat16* __restrict__ h1out) {
  __shared__ char sm[8192];
  const int tid = threadIdx.x;
  const int l = tid & 63, wv = tid >> 6;
  const int c = l & 15, lg = l >> 4;
  const int role = wv >> 3, rw = wv & 7;
  const int B0 = blockIdx.x * 4;
  const int m_ = 16 * rw + c;
  const int row = 4 * lg;
  const int wf8 = row * 128 + (((m_ >> 3) ^ row) << 3) + (m_ & 7);

  for (int e = tid * 4; e < 8192; e += 1024 * 4) *(int*)(sm + e) = 0;

  auto AFRAG = [&](int base) -> v8i {
    union { unsigned long long q[4]; v8i v; } u;
#pragma unroll
    for (int t = 0; t < 4; t++)
      u.q[t] = *(const unsigned long long*)(
          sm + base + c * 128 + ((((lg * 4 + t) ^ c) & 15) << 3));
    return u.v;
  };

  if (role == 0) {
    // ================= L0 =================
    v8i breg[4];                             // fp8 scaled W0h B-frags
#pragma unroll
    for (int g = 0; g < 4; g++) {
      int n = g * 128 + m_;
      float fac = (g == 2) ? L2E2 : NL2E;
      union { unsigned long long q[4]; v8i v; } u;
#pragma unroll
      for (int t = 0; t < 4; t++) {
        unsigned long long w = 0ull;
#pragma unroll
        for (int j = 0; j < 8; j++) {
          int k = lg * 32 + t * 8 + j;
          w |= (unsigned long long)f2e4m3(W0f[(size_t)(FIN + k) * 512 + n] * fac) << (8 * j);
        }
        u.q[t] = w;
      }
      breg[g] = u.v;
    }

    uint2 zA, zB, zC;
    auto ZLD = [&](int t) -> uint2 {
      return *(const uint2*)(Z + ((size_t)t * 128 + B0 + lg) * 512 + m_ * 4);
    };
    zA = ZLD(0); zB = ZLD(1);
    float cst = 0.f;
    v4f acc[4];
#pragma unroll
    for (int g = 0; g < 4; g++) acc[g] = (v4f){0.f, 0.f, 0.f, 0.f};
    __syncthreads();

    for (int s = 0; s < NT; s++) {
      v8i av = AFRAG(((s + 1) & 1) * 2048);  // h0(s-1) fp8
      // inject z' via C-in (components 1..3 stay 0 forever: pad A-rows are 0)
      acc[0][0] = u2f(zA.x << 16);
      acc[1][0] = u2f(zA.x & 0xffff0000u);
      acc[2][0] = u2f(zA.y << 16);
      acc[3][0] = u2f(zA.y & 0xffff0000u);
      __builtin_amdgcn_s_setprio(1);
#pragma unroll
      for (int g = 0; g < 4; g++) acc[g] = MFMA_MX(av, breg[g], acc[g]);
      __builtin_amdgcn_s_setprio(0);
      if (s + 2 < NT) zC = ZLD(s + 2);

      float ei = exp2a(acc[0][0]);           // = exp(-xi)
      float ef = exp2a(acc[1][0]);           // = exp(-xf)
      float eg = exp2a(acc[2][0]);           // = exp(2*xg)
      float eo = exp2a(acc[3][0]);           // = exp(-xo)
      float cn = cst * __builtin_amdgcn_rcpf(1.f + ef)
               + (eg - 1.f) * __builtin_amdgcn_rcpf((1.f + ei) * (eg + 1.f));
      cst = cn;
      float ec = exp2a(L2E2 * cn);           // = exp(2*cn)
      float hv = (ec - 1.f) * __builtin_amdgcn_rcpf((1.f + eo) * (ec + 1.f));
      *(unsigned char*)(sm + (s & 1) * 2048 + wf8) = (unsigned char)cvtfp8(hv);
      zA = zB; zB = zC;
      sync_lds();
    }
    sync_lds();                              // L1 tail step
  } else {
    // ================= L1 (one step behind) =================
    v8i bregH[4], bregX[4];                  // fp8 scaled B-frags
#pragma unroll
    for (int g = 0; g < 4; g++) {
      int n = g * 128 + m_;
      float fac = (g == 2) ? L2E2 : NL2E;
      union { unsigned long long q[4]; v8i v; } uh, ux;
#pragma unroll
      for (int t = 0; t < 4; t++) {
        unsigned long long wh = 0ull, wx = 0ull;
#pragma unroll
        for (int j = 0; j < 8; j++) {
          int k = lg * 32 + t * 8 + j;
          wh |= (unsigned long long)f2e4m3(W1f[(size_t)(128 + k) * 512 + n] * fac) << (8 * j);
          wx |= (unsigned long long)f2e4m3(W1f[(size_t)k * 512 + n] * fac) << (8 * j);
        }
        uh.q[t] = wh; ux.q[t] = wx;
      }
      bregH[g] = uh.v; bregX[g] = ux.v;
    }
    float bq[4];
#pragma unroll
    for (int g = 0; g < 4; g++) {
      float fac = (g == 2) ? L2E2 : NL2E;
      bq[g] = (b1[g * 128 + m_] + ((g == 1) ? 1.0f : 0.0f)) * fac;
    }
    float cst = 0.f;
    v4f acc[4];
#pragma unroll
    for (int g = 0; g < 4; g++) acc[g] = (v4f){bq[g], bq[g], bq[g], bq[g]};
    __syncthreads();
    sync_lds();                              // skip s=0 (idle)

    for (int s = 1; s <= NT; s++) {
      v8i ah = AFRAG(4096 + (s & 1) * 2048); // h1(s-2) fp8
      v8i ax = AFRAG(((s + 1) & 1) * 2048);  // h0(s-1) fp8
#pragma unroll
      for (int g = 0; g < 4; g++) acc[g][0] = bq[g];
      __builtin_amdgcn_s_setprio(1);
#pragma unroll
      for (int g = 0; g < 4; g++) acc[g] = MFMA_MX(ah, bregH[g], acc[g]);
#pragma unroll
      for (int g = 0; g < 4; g++) acc[g] = MFMA_MX(ax, bregX[g], acc[g]);
      __builtin_amdgcn_s_setprio(0);

      float ei = exp2a(acc[0][0]);
      float ef = exp2a(acc[1][0]);
      float eg = exp2a(acc[2][0]);
      float eo = exp2a(acc[3][0]);
      float cn = cst * __builtin_amdgcn_rcpf(1.f + ef)
               + (eg - 1.f) * __builtin_amdgcn_rcpf((1.f + ei) * (eg + 1.f));
      cst = cn;
      float ec = exp2a(L2E2 * cn);
      float hv = (ec - 1.f) * __builtin_amdgcn_rcpf((1.f + eo) * (ec + 1.f));
      *(unsigned char*)(sm + 4096 + ((s + 1) & 1) * 2048 + wf8) =
          (unsigned char)cvtfp8(hv);
      union { short s; __hip_bfloat16 h; } cv; cv.s = f2b(hv);
      h1out[((size_t)(s - 1) * 128 + B0 + lg) * 128 + m_] = cv.h;
      sync_lds();
    }
  }
}

// --------------------------------------------------------------------------
// K5: heads. WG = 64 rows (4 waves x 16). Logits GEMM [64x128]@[128x368] then
// per-row softmax/xent/argmax + value head; atomic partial sums.
// --------------------------------------------------------------------------
__global__ __launch_bounds__(256) void k_heads(
    const __hip_bfloat16* __restrict__ Hh, const __hip_bfloat16* __restrict__ WpT,
    const float* __restrict__ bpp, const float* __restrict__ Wv,
    const float* __restrict__ bv, const int* __restrict__ moves,
    const float* __restrict__ values, float* __restrict__ accum) {
  __shared__ char sm[110592];                // A 16KB @0, B 94208B @16384
  const int tid = threadIdx.x;
  const int l = tid & 63, wm = tid >> 6;
  const int c = l & 15, lg = l >> 4;
  const int r0 = blockIdx.x * 64;

#pragma unroll
  for (int i = 0; i < 4; i++) {
    int idx = i * 4096 + tid * 16;
    int row = idx >> 8, colb = idx & 255;
    uint4 v = *(const uint4*)((const char*)Hh + (size_t)r0 * 256 + idx);
    *(uint4*)(sm + row * 256 + (colb ^ ((row & 7) << 4))) = v;
  }
#pragma unroll
  for (int i = 0; i < 23; i++) {
    int idx = i * 4096 + tid * 16;
    int row = idx >> 8, colb = idx & 255;
    uint4 v = *(const uint4*)((const char*)WpT + idx);
    *(uint4*)(sm + 16384 + row * 256 + (colb ^ ((row & 7) << 4))) = v;
  }
  __syncthreads();

  v4f acc[23];
  v4f z4 = {0.f, 0.f, 0.f, 0.f};
#pragma unroll
  for (int q = 0; q < 23; q++) acc[q] = z4;
#pragma unroll
  for (int kk = 0; kk < 4; kk++) {
    int bir = kk * 64 + lg * 16;
    int ar = wm * 16 + c;
    v8s a = *(v8s*)(sm + ar * 256 + (bir ^ ((ar & 7) << 4)));
#pragma unroll
    for (int q = 0; q < 23; q++) {
      int n = q * 16 + c;
      v8s b = *(v8s*)(sm + 16384 + n * 256 + (bir ^ ((n & 7) << 4)));
      acc[q] = MFMA_B16(a, b, acc[q]);
    }
  }
  float bq[23];
#pragma unroll
  for (int q = 0; q < 23; q++) bq[q] = bpp[q * 16 + c];

  float tp = 0.f, tv = 0.f, ta = 0.f, tn = 0.f;
#pragma unroll
  for (int j = 0; j < 4; j++) {
    int rloc = lg * 4 + j;
    int r = r0 + wm * 16 + rloc;
    int t = r >> 7, b = r & 127;
    int mv = moves[(size_t)b * NT + t];
    float val = values[(size_t)b * NT + t];
    float msk = (val != -9.0f) ? 1.f : 0.f;

    float pmax = -3.0e38f;
#pragma unroll
    for (int q = 0; q < 23; q++) pmax = fmaxf(pmax, acc[q][j] + bq[q]);
#pragma unroll
    for (int d = 1; d < 16; d <<= 1) pmax = fmaxf(pmax, __shfl_xor(pmax, d, 64));
    float ps = 0.f;
#pragma unroll
    for (int q = 0; q < 23; q++) ps += __expf((acc[q][j] + bq[q]) - pmax);
#pragma unroll
    for (int d = 1; d < 16; d <<= 1) ps += __shfl_xor(ps, d, 64);
    float lse = pmax + __logf(ps);

    int qm = mv >> 4, cm = mv & 15;
    float mlv = 0.f;
#pragma unroll
    for (int q = 0; q < 23; q++) if (q == qm) mlv = acc[q][j] + bq[q];
    mlv = __shfl(mlv, (l & 48) + cm, 64);
    float xent = lse - mlv;

    float amx = -3.0e38f; int aix = 0;
#pragma unroll
    for (int q = 0; q < 23; q++) {
      float v = acc[q][j] + bq[q];
      if (v > amx) { amx = v; aix = q * 16 + c; }
    }
#pragma unroll
    for (int d = 1; d < 16; d <<= 1) {
      float ov = __shfl_xor(amx, d, 64);
      int oi = __shfl_xor(aix, d, 64);
      if (ov > amx || (ov == amx && oi < aix)) { amx = ov; aix = oi; }
    }

    float pd = 0.f;
    int vrow = wm * 16 + rloc;
#pragma unroll
    for (int i = 0; i < 8; i++) {
      int k = c * 8 + i;
      short hv = *(short*)(sm + vrow * 256 + ((k * 2) ^ ((vrow & 7) << 4)));
      pd += b2f((unsigned short)hv) * Wv[k];
    }
#pragma unroll
    for (int d = 1; d < 16; d <<= 1) pd += __shfl_xor(pd, d, 64);
    float eo = __expf(2.f * (pd + bv[0]));
    float win = (eo - 1.f) * __builtin_amdgcn_rcpf(eo + 1.f);
    float dv = win - val;

    if (c == 0) {
      tp += msk * xent;
      tv += msk * dv * dv;
      ta += (aix == mv) ? 1.f : 0.f;
      tn += msk;
    }
  }
  tp += __shfl_xor(tp, 16, 64); tp += __shfl_xor(tp, 32, 64);
  tv += __shfl_xor(tv, 16, 64); tv += __shfl_xor(tv, 32, 64);
  ta += __shfl_xor(ta, 16, 64); ta += __shfl_xor(ta, 32, 64);
  tn += __shfl_xor(tn, 16, 64); tn += __shfl_xor(tn, 32, 64);
  if (l == 0) {
    atomicAdd(accum + 0, tp);
    atomicAdd(accum + 1, tv);
    atomicAdd(accum + 2, ta);
    atomicAdd(accum + 3, tn);
  }
}

__global__ void k_final(const float* __restrict__ accum, float* __restrict__ out) {
  if (threadIdx.x == 0) {
    float nm = accum[3];
    out[0] = accum[0] / nm;
    out[1] = accum[1] / nm;
    out[2] = accum[2] / 65536.0f;
  }
}

// --------------------------------------------------------------------------
extern "C" void kernel_launch(void* const* d_in, const int* in_sizes, int n_in,
                              void* d_out, int out_size, void* d_ws, size_t ws_size,
                              hipStream_t stream) {
  (void)in_sizes; (void)n_in; (void)out_size; (void)ws_size;
  const float* states = (const float*)d_in[0];
  const int*   moves  = (const int*)d_in[1];
  const float* values = (const float*)d_in[2];
  const float* W0 = (const float*)d_in[3];
  const float* b0 = (const float*)d_in[4];
  const float* W1 = (const float*)d_in[5];
  const float* b1 = (const float*)d_in[6];
  const float* Wp = (const float*)d_in[7];
  const float* bp = (const float*)d_in[8];
  const float* Wv = (const float*)d_in[9];
  const float* bv = (const float*)d_in[10];
  char* ws = (char*)d_ws;

  __hip_bfloat16* zbuf = (__hip_bfloat16*)(ws + OFF_Z);
  __hip_bfloat16* h1   = (__hip_bfloat16*)(ws + OFF_H1);
  __hip_bfloat16* W0xT = (__hip_bfloat16*)(ws + OFF_W0XT);
  __hip_bfloat16* WpT  = (__hip_bfloat16*)(ws + OFF_WPT);
  float* b0p = (float*)(ws + OFF_B0P);
  float* bpp = (float*)(ws + OFF_BPP);
  float* acc = (float*)(ws + OFF_ACC);

  k_conv_weights<<<956, 256, 0, stream>>>(W0, b0, Wp, bp, ws);
  k_gemm<KP0, true><<<dim3(512, 4), 256, 0, stream>>>(states, W0xT, b0p, zbuf);
  k_scan12<<<32, 1024, 0, stream>>>(zbuf, W0, W1, b1, h1);
  k_heads<<<1024, 256, 0, stream>>>(h1, WpT, bpp, Wv, bv, moves, values, acc);
  k_final<<<1, 1, 0, stream>>>(acc, (float*)d_out);
}

// Round 10
// 1053.190 us; speedup vs baseline: 2.6924x; 1.0662x over previous
//
#include <hip/hip_runtime.h>
#include <hip/hip_bf16.h>
#include <stdint.h>

// ---------------------------------------------------------------------------
// RNN_79164837199890: 2-layer LSTM (B=128,T=512,H=128) + policy/value heads.
// R10: R7 schedule exactly (no setprio — m190 regime: lockstep waves; no
// loop-carried MFMA C operand — fresh acc vector per step). Kept from R9:
// log2e/sign folded into scan weights/biases/z (exp -> bare v_exp_f32 via
// __builtin_amdgcn_exp2f) and 1-op fp8 encode (v_cvt_pk_fp8_f32 asm).
// ---------------------------------------------------------------------------

typedef short v8s __attribute__((ext_vector_type(8)));   // 8 x bf16 fragment
typedef float v4f __attribute__((ext_vector_type(4)));   // MFMA accumulator
typedef int   v8i __attribute__((ext_vector_type(8)));   // 32 x fp8 fragment

#define MFMA_B16(a,b,c) __builtin_amdgcn_mfma_f32_16x16x32_bf16((a),(b),(c),0,0,0)
#define MFMA_MX(a,b,c) \
  __builtin_amdgcn_mfma_scale_f32_16x16x128_f8f6f4((a),(b),(c),0,0,0,0x7F7F7F7F,0,0x7F7F7F7F)

#define NT     512
#define FIN    361
#define KP0    384
#define NPC    362
#define NPP    368
// gate scale factors: xi,xf,xo -> -log2e (exp(-x)=2^(x')); xg -> +2log2e
#define NL2E  (-1.4426950408889634f)
#define L2E2  (2.8853900817779268f)

// workspace offsets (bytes)
#define OFF_Z    ((size_t)0)          // 65536*512*2 = 67108864 (z0x', gate-packed, scaled)
#define OFF_H1   ((size_t)83886080)   // 65536*128*2 = 16777216
#define OFF_W0XT ((size_t)100663296)  // 512*384*2 = 393216
#define OFF_WPT  ((size_t)101187584)  // 368*128*2 = 94208
#define OFF_B0P  ((size_t)101281792)  // 512*4
#define OFF_BPP  ((size_t)101285888)  // 368*4
#define OFF_ACC  ((size_t)101287936)  // 4 floats

static __device__ __forceinline__ short f2b(float f) {
  __hip_bfloat16 h = __float2bfloat16(f);
  union { __hip_bfloat16 h; short s; } cv; cv.h = h; return cv.s;
}
static __device__ __forceinline__ float b2f(unsigned int lo16) {
  union { unsigned u; float f; } cv; cv.u = lo16 << 16; return cv.f;
}
static __device__ __forceinline__ float u2f(unsigned int bits) {
  union { unsigned u; float f; } cv; cv.u = bits; return cv.f;
}
// f32 -> OCP e4m3fn with RNE (one-time weight packs)
static __device__ __forceinline__ unsigned f2e4m3(float f) {
  union { float f; unsigned u; } cv; cv.f = f;
  unsigned s = (cv.u >> 31) << 7;
  float a = fabsf(f);
  a = fminf(a, 448.f);
  unsigned code;
  if (a >= 0.015625f) {
    union { float f; unsigned u; } m; m.f = a;
    unsigned u = m.u + 0x7FFFF + ((m.u >> 20) & 1);
    code = (u >> 20) - 960;
    if (code > 126u) code = 126u;
  } else {
    code = (unsigned)rintf(a * 512.f);
  }
  return s | code;
}
// per-step fp8 encode: 1 VALU op
static __device__ __forceinline__ unsigned cvtfp8(float f) {
  unsigned r = 0;
  asm("v_cvt_pk_fp8_f32 %0, %1, %2" : "+v"(r) : "v"(f), "v"(f));
  return r & 0xffu;
}
#define EXP2(x) __builtin_amdgcn_exp2f(x)

// Raw barrier with LDS-only drain (global stores/loads keep floating).
static __device__ __forceinline__ void sync_lds() {
  __builtin_amdgcn_sched_barrier(0);
  asm volatile("s_waitcnt lgkmcnt(0)" ::: "memory");
  __builtin_amdgcn_s_barrier();
  __builtin_amdgcn_sched_barrier(0);
}

// --------------------------------------------------------------------------
// K0: weight conversion. Packed gate order: col' = m*4+g  <->  n = m + 128*g
// Forget +1.0 folded into b0p; gate log2e factors folded into W0xT/b0p.
// --------------------------------------------------------------------------
__global__ __launch_bounds__(256) void k_conv_weights(
    const float* __restrict__ W0, const float* __restrict__ b0,
    const float* __restrict__ Wp, const float* __restrict__ bp,
    char* __restrict__ ws) {
  int idx = blockIdx.x * 256 + threadIdx.x;
  __hip_bfloat16* W0xT = (__hip_bfloat16*)(ws + OFF_W0XT);
  __hip_bfloat16* WpT  = (__hip_bfloat16*)(ws + OFF_WPT);
  float* b0p = (float*)(ws + OFF_B0P);
  float* bpp = (float*)(ws + OFF_BPP);
  float* acc = (float*)(ws + OFF_ACC);

  if (idx < 196608) {                       // W0xT [512 cols'][384 k], scaled
    int np = idx / 384, k = idx - np * 384;
    int n = (np >> 2) + 128 * (np & 3);
    float fac = ((np & 3) == 2) ? L2E2 : NL2E;
    float v = (k < FIN) ? W0[(size_t)k * 512 + n] * fac : 0.f;
    W0xT[idx] = __float2bfloat16(v);
    return;
  }
  idx -= 196608;
  if (idx < 47104) {                        // WpT [368 p][128 k]
    int p = idx >> 7, k = idx & 127;
    WpT[idx] = __float2bfloat16(p < NPC ? Wp[(size_t)k * NPC + p] : 0.f);
    return;
  }
  idx -= 47104;
  if (idx < 512) {                          // b0p packed: (+1 forget) * fac
    int g = idx & 3;
    int n = (idx >> 2) + 128 * g;
    float fac = (g == 2) ? L2E2 : NL2E;
    b0p[idx] = (b0[n] + ((g == 1) ? 1.0f : 0.0f)) * fac;
    return;
  }
  idx -= 512;
  if (idx < NPP) { bpp[idx] = (idx < NPC) ? bp[idx] : -1e30f; return; }
  idx -= NPP;
  if (idx < 4) { acc[idx] = 0.f; return; }
}

// --------------------------------------------------------------------------
// K1: C[r, col'] = A[r,:] @ BT[col',:]^T + bias[col'],  C bf16 [65536][512]
// (B/bias pre-scaled by gate factors => C = z' directly.)
// --------------------------------------------------------------------------
template<int KTOT, bool AF32>
__global__ __launch_bounds__(256) void k_gemm(
    const void* __restrict__ Ap, const __hip_bfloat16* __restrict__ BT,
    const float* __restrict__ bias, __hip_bfloat16* __restrict__ C) {
  __shared__ char sm[65536];                 // A: 2x16KB @0, B: 2x16KB @32768
  const int tid = threadIdx.x;
  const int l = tid & 63, wm = tid >> 6;
  const int c = l & 15, lg = l >> 4;
  const int m0 = blockIdx.x * 128;
  const int n0 = blockIdx.y * 128;
  constexpr int NS = KTOT / 64;

  uint4 ra[4], rb[4];
  float fa[32];

  auto LD = [&](int ks) {
#pragma unroll
    for (int i = 0; i < 4; i++) {
      int idx = i * 4096 + tid * 16;
      int row = idx >> 7, colb = idx & 127;
      if constexpr (AF32) {
        int r = m0 + row;
        const float* src = (const float*)Ap + ((size_t)(r & 127) * NT + (r >> 7)) * FIN;
        int kb = ks * 64 + (colb >> 1);
#pragma unroll
        for (int u = 0; u < 8; u++) {
          int kf = kb + u;
          fa[i * 8 + u] = (kf < FIN) ? src[kf] : 0.f;
        }
      } else {
        ra[i] = *(const uint4*)((const char*)Ap + ((size_t)(m0 + row) * KTOT + ks * 64) * 2 + colb);
      }
      rb[i] = *(const uint4*)((const char*)BT + ((size_t)(n0 + row) * KTOT + ks * 64) * 2 + colb);
    }
  };
  auto ST = [&](int bsel) {
#pragma unroll
    for (int i = 0; i < 4; i++) {
      int idx = i * 4096 + tid * 16;
      int row = idx >> 7, colb = idx & 127;
      int sw = colb ^ ((row & 7) << 4);
      if constexpr (AF32) {
        v8s w;
#pragma unroll
        for (int u = 0; u < 8; u++) w[u] = f2b(fa[i * 8 + u]);
        *(v8s*)(sm + bsel * 16384 + row * 128 + sw) = w;
      } else {
        *(uint4*)(sm + bsel * 16384 + row * 128 + sw) = ra[i];
      }
      *(uint4*)(sm + 32768 + bsel * 16384 + row * 128 + sw) = rb[i];
    }
  };

  v4f acc[2][8];
  v4f z4 = {0.f, 0.f, 0.f, 0.f};
#pragma unroll
  for (int mt = 0; mt < 2; mt++)
#pragma unroll
    for (int nt = 0; nt < 8; nt++) acc[mt][nt] = z4;

  LD(0); ST(0);
  __syncthreads();
  for (int ks = 0; ks < NS; ks++) {
    if (ks + 1 < NS) LD(ks + 1);
    const int bsel = ks & 1;
#pragma unroll
    for (int kk = 0; kk < 2; kk++) {
      int bir = kk * 64 + lg * 16;
      v8s af[2];
#pragma unroll
      for (int mt = 0; mt < 2; mt++) {
        int row = wm * 32 + mt * 16 + c;
        af[mt] = *(v8s*)(sm + bsel * 16384 + row * 128 + (bir ^ ((row & 7) << 4)));
      }
#pragma unroll
      for (int nt = 0; nt < 8; nt++) {
        int n = nt * 16 + c;
        v8s bf = *(v8s*)(sm + 32768 + bsel * 16384 + n * 128 + (bir ^ ((n & 7) << 4)));
#pragma unroll
        for (int mt = 0; mt < 2; mt++) acc[mt][nt] = MFMA_B16(af[mt], bf, acc[mt][nt]);
      }
    }
    if (ks + 1 < NS) ST((ks + 1) & 1);
    __syncthreads();
  }

#pragma unroll
  for (int mt = 0; mt < 2; mt++)
#pragma unroll
    for (int nt = 0; nt < 8; nt++) {
      int colp = n0 + nt * 16 + c;
      float bs = bias[colp];
#pragma unroll
      for (int j = 0; j < 4; j++) {
        int row = m0 + wm * 32 + mt * 16 + lg * 4 + j;
        C[(size_t)row * 512 + colp] = __float2bfloat16(acc[mt][nt][j] + bs);
      }
    }
}

// --------------------------------------------------------------------------
// K2: merged 2-layer scan, MX K=128 fp8 (R7 schedule). 32 WGs x 16 waves.
// role = wv>>3 (0: L0; 1: L1 one step behind). lane: m=16rw+c, batch B0+lg
// (M-row 4lg), 1 cell/lane. LDS: h0 fp8 dbuf @0, h1 fp8 dbuf @4096.
// Weights pre-scaled by gate log2e factors; fresh acc vector every step.
// --------------------------------------------------------------------------
__global__ __launch_bounds__(1024, 4) void k_scan12(
    const __hip_bfloat16* __restrict__ Z, const float* __restrict__ W0f,
    const float* __restrict__ W1f, const float* __restrict__ b1,
    __hip_bfloat16* __restrict__ h1out) {
  __shared__ char sm[8192];
  const int tid = threadIdx.x;
  const int l = tid & 63, wv = tid >> 6;
  const int c = l & 15, lg = l >> 4;
  const int role = wv >> 3, rw = wv & 7;
  const int B0 = blockIdx.x * 4;
  const int m_ = 16 * rw + c;
  const int row = 4 * lg;
  const int wf8 = row * 128 + (((m_ >> 3) ^ row) << 3) + (m_ & 7);

  for (int e = tid * 4; e < 8192; e += 1024 * 4) *(int*)(sm + e) = 0;

  auto AFRAG = [&](int base) -> v8i {
    union { unsigned long long q[4]; v8i v; } u;
#pragma unroll
    for (int t = 0; t < 4; t++)
      u.q[t] = *(const unsigned long long*)(
          sm + base + c * 128 + ((((lg * 4 + t) ^ c) & 15) << 3));
    return u.v;
  };

  if (role == 0) {
    // ================= L0 =================
    v8i breg[4];                             // fp8 scaled W0h B-frags
#pragma unroll
    for (int g = 0; g < 4; g++) {
      int n = g * 128 + m_;
      float fac = (g == 2) ? L2E2 : NL2E;
      union { unsigned long long q[4]; v8i v; } u;
#pragma unroll
      for (int t = 0; t < 4; t++) {
        unsigned long long w = 0ull;
#pragma unroll
        for (int j = 0; j < 8; j++) {
          int k = lg * 32 + t * 8 + j;
          w |= (unsigned long long)f2e4m3(W0f[(size_t)(FIN + k) * 512 + n] * fac) << (8 * j);
        }
        u.q[t] = w;
      }
      breg[g] = u.v;
    }

    uint2 zA, zB, zC;
    auto ZLD = [&](int t) -> uint2 {
      return *(const uint2*)(Z + ((size_t)t * 128 + B0 + lg) * 512 + m_ * 4);
    };
    zA = ZLD(0); zB = ZLD(1);
    float cst = 0.f;
    __syncthreads();

    for (int s = 0; s < NT; s++) {
      v8i av = AFRAG(((s + 1) & 1) * 2048);  // h0(s-1) fp8
      v4f acc[4];                            // fresh vectors (no loop-carry)
      acc[0] = (v4f){u2f(zA.x << 16),        0.f, 0.f, 0.f};
      acc[1] = (v4f){u2f(zA.x & 0xffff0000u), 0.f, 0.f, 0.f};
      acc[2] = (v4f){u2f(zA.y << 16),        0.f, 0.f, 0.f};
      acc[3] = (v4f){u2f(zA.y & 0xffff0000u), 0.f, 0.f, 0.f};
#pragma unroll
      for (int g = 0; g < 4; g++) acc[g] = MFMA_MX(av, breg[g], acc[g]);
      if (s + 2 < NT) zC = ZLD(s + 2);

      float ei = EXP2(acc[0][0]);            // = exp(-xi)
      float ef = EXP2(acc[1][0]);            // = exp(-xf)
      float eg = EXP2(acc[2][0]);            // = exp(2*xg)
      float eo = EXP2(acc[3][0]);            // = exp(-xo)
      float cn = cst * __builtin_amdgcn_rcpf(1.f + ef)
               + (eg - 1.f) * __builtin_amdgcn_rcpf((1.f + ei) * (eg + 1.f));
      cst = cn;
      float ec = EXP2(L2E2 * cn);            // = exp(2*cn)
      float hv = (ec - 1.f) * __builtin_amdgcn_rcpf((1.f + eo) * (ec + 1.f));
      *(unsigned char*)(sm + (s & 1) * 2048 + wf8) = (unsigned char)cvtfp8(hv);
      zA = zB; zB = zC;
      sync_lds();
    }
    sync_lds();                              // L1 tail step
  } else {
    // ================= L1 (one step behind) =================
    v8i bregH[4], bregX[4];                  // fp8 scaled B-frags
#pragma unroll
    for (int g = 0; g < 4; g++) {
      int n = g * 128 + m_;
      float fac = (g == 2) ? L2E2 : NL2E;
      union { unsigned long long q[4]; v8i v; } uh, ux;
#pragma unroll
      for (int t = 0; t < 4; t++) {
        unsigned long long wh = 0ull, wx = 0ull;
#pragma unroll
        for (int j = 0; j < 8; j++) {
          int k = lg * 32 + t * 8 + j;
          wh |= (unsigned long long)f2e4m3(W1f[(size_t)(128 + k) * 512 + n] * fac) << (8 * j);
          wx |= (unsigned long long)f2e4m3(W1f[(size_t)k * 512 + n] * fac) << (8 * j);
        }
        uh.q[t] = wh; ux.q[t] = wx;
      }
      bregH[g] = uh.v; bregX[g] = ux.v;
    }
    float bq[4];
#pragma unroll
    for (int g = 0; g < 4; g++) {
      float fac = (g == 2) ? L2E2 : NL2E;
      bq[g] = (b1[g * 128 + m_] + ((g == 1) ? 1.0f : 0.0f)) * fac;
    }
    float cst = 0.f;
    __syncthreads();
    sync_lds();                              // skip s=0 (idle)

    for (int s = 1; s <= NT; s++) {
      v8i ah = AFRAG(4096 + (s & 1) * 2048); // h1(s-2) fp8
      v8i ax = AFRAG(((s + 1) & 1) * 2048);  // h0(s-1) fp8
      v4f acc[4];                            // fresh vectors (no loop-carry)
#pragma unroll
      for (int g = 0; g < 4; g++) acc[g] = (v4f){bq[g], 0.f, 0.f, 0.f};
#pragma unroll
      for (int g = 0; g < 4; g++) acc[g] = MFMA_MX(ah, bregH[g], acc[g]);
#pragma unroll
      for (int g = 0; g < 4; g++) acc[g] = MFMA_MX(ax, bregX[g], acc[g]);

      float ei = EXP2(acc[0][0]);
      float ef = EXP2(acc[1][0]);
      float eg = EXP2(acc[2][0]);
      float eo = EXP2(acc[3][0]);
      float cn = cst * __builtin_amdgcn_rcpf(1.f + ef)
               + (eg - 1.f) * __builtin_amdgcn_rcpf((1.f + ei) * (eg + 1.f));
      cst = cn;
      float ec = EXP2(L2E2 * cn);
      float hv = (ec - 1.f) * __builtin_amdgcn_rcpf((1.f + eo) * (ec + 1.f));
      *(unsigned char*)(sm + 4096 + ((s + 1) & 1) * 2048 + wf8) =
          (unsigned char)cvtfp8(hv);
      union { short s; __hip_bfloat16 h; } cv; cv.s = f2b(hv);
      h1out[((size_t)(s - 1) * 128 + B0 + lg) * 128 + m_] = cv.h;
      sync_lds();
    }
  }
}

// --------------------------------------------------------------------------
// K5: heads. WG = 64 rows (4 waves x 16). Logits GEMM [64x128]@[128x368] then
// per-row softmax/xent/argmax + value head; atomic partial sums.
// --------------------------------------------------------------------------
__global__ __launch_bounds__(256) void k_heads(
    const __hip_bfloat16* __restrict__ Hh, const __hip_bfloat16* __restrict__ WpT,
    const float* __restrict__ bpp, const float* __restrict__ Wv,
    const float* __restrict__ bv, const int* __restrict__ moves,
    const float* __restrict__ values, float* __restrict__ accum) {
  __shared__ char sm[110592];                // A 16KB @0, B 94208B @16384
  const int tid = threadIdx.x;
  const int l = tid & 63, wm = tid >> 6;
  const int c = l & 15, lg = l >> 4;
  const int r0 = blockIdx.x * 64;

#pragma unroll
  for (int i = 0; i < 4; i++) {
    int idx = i * 4096 + tid * 16;
    int row = idx >> 8, colb = idx & 255;
    uint4 v = *(const uint4*)((const char*)Hh + (size_t)r0 * 256 + idx);
    *(uint4*)(sm + row * 256 + (colb ^ ((row & 7) << 4))) = v;
  }
#pragma unroll
  for (int i = 0; i < 23; i++) {
    int idx = i * 4096 + tid * 16;
    int row = idx >> 8, colb = idx & 255;
    uint4 v = *(const uint4*)((const char*)WpT + idx);
    *(uint4*)(sm + 16384 + row * 256 + (colb ^ ((row & 7) << 4))) = v;
  }
  __syncthreads();

  v4f acc[23];
  v4f z4 = {0.f, 0.f, 0.f, 0.f};
#pragma unroll
  for (int q = 0; q < 23; q++) acc[q] = z4;
#pragma unroll
  for (int kk = 0; kk < 4; kk++) {
    int bir = kk * 64 + lg * 16;
    int ar = wm * 16 + c;
    v8s a = *(v8s*)(sm + ar * 256 + (bir ^ ((ar & 7) << 4)));
#pragma unroll
    for (int q = 0; q < 23; q++) {
      int n = q * 16 + c;
      v8s b = *(v8s*)(sm + 16384 + n * 256 + (bir ^ ((n & 7) << 4)));
      acc[q] = MFMA_B16(a, b, acc[q]);
    }
  }
  float bq[23];
#pragma unroll
  for (int q = 0; q < 23; q++) bq[q] = bpp[q * 16 + c];

  float tp = 0.f, tv = 0.f, ta = 0.f, tn = 0.f;
#pragma unroll
  for (int j = 0; j < 4; j++) {
    int rloc = lg * 4 + j;
    int r = r0 + wm * 16 + rloc;
    int t = r >> 7, b = r & 127;
    int mv = moves[(size_t)b * NT + t];
    float val = values[(size_t)b * NT + t];
    float msk = (val != -9.0f) ? 1.f : 0.f;

    float pmax = -3.0e38f;
#pragma unroll
    for (int q = 0; q < 23; q++) pmax = fmaxf(pmax, acc[q][j] + bq[q]);
#pragma unroll
    for (int d = 1; d < 16; d <<= 1) pmax = fmaxf(pmax, __shfl_xor(pmax, d, 64));
    float ps = 0.f;
#pragma unroll
    for (int q = 0; q < 23; q++) ps += __expf((acc[q][j] + bq[q]) - pmax);
#pragma unroll
    for (int d = 1; d < 16; d <<= 1) ps += __shfl_xor(ps, d, 64);
    float lse = pmax + __logf(ps);

    int qm = mv >> 4, cm = mv & 15;
    float mlv = 0.f;
#pragma unroll
    for (int q = 0; q < 23; q++) if (q == qm) mlv = acc[q][j] + bq[q];
    mlv = __shfl(mlv, (l & 48) + cm, 64);
    float xent = lse - mlv;

    float amx = -3.0e38f; int aix = 0;
#pragma unroll
    for (int q = 0; q < 23; q++) {
      float v = acc[q][j] + bq[q];
      if (v > amx) { amx = v; aix = q * 16 + c; }
    }
#pragma unroll
    for (int d = 1; d < 16; d <<= 1) {
      float ov = __shfl_xor(amx, d, 64);
      int oi = __shfl_xor(aix, d, 64);
      if (ov > amx || (ov == amx && oi < aix)) { amx = ov; aix = oi; }
    }

    float pd = 0.f;
    int vrow = wm * 16 + rloc;
#pragma unroll
    for (int i = 0; i < 8; i++) {
      int k = c * 8 + i;
      short hv = *(short*)(sm + vrow * 256 + ((k * 2) ^ ((vrow & 7) << 4)));
      pd += b2f((unsigned short)hv) * Wv[k];
    }
#pragma unroll
    for (int d = 1; d < 16; d <<= 1) pd += __shfl_xor(pd, d, 64);
    float eo = __expf(2.f * (pd + bv[0]));
    float win = (eo - 1.f) * __builtin_amdgcn_rcpf(eo + 1.f);
    float dv = win - val;

    if (c == 0) {
      tp += msk * xent;
      tv += msk * dv * dv;
      ta += (aix == mv) ? 1.f : 0.f;
      tn += msk;
    }
  }
  tp += __shfl_xor(tp, 16, 64); tp += __shfl_xor(tp, 32, 64);
  tv += __shfl_xor(tv, 16, 64); tv += __shfl_xor(tv, 32, 64);
  ta += __shfl_xor(ta, 16, 64); ta += __shfl_xor(ta, 32, 64);
  tn += __shfl_xor(tn, 16, 64); tn += __shfl_xor(tn, 32, 64);
  if (l == 0) {
    atomicAdd(accum + 0, tp);
    atomicAdd(accum + 1, tv);
    atomicAdd(accum + 2, ta);
    atomicAdd(accum + 3, tn);
  }
}

__global__ void k_final(const float* __restrict__ accum, float* __restrict__ out) {
  if (threadIdx.x == 0) {
    float nm = accum[3];
    out[0] = accum[0] / nm;
    out[1] = accum[1] / nm;
    out[2] = accum[2] / 65536.0f;
  }
}

// --------------------------------------------------------------------------
extern "C" void kernel_launch(void* const* d_in, const int* in_sizes, int n_in,
                              void* d_out, int out_size, void* d_ws, size_t ws_size,
                              hipStream_t stream) {
  (void)in_sizes; (void)n_in; (void)out_size; (void)ws_size;
  const float* states = (const float*)d_in[0];
  const int*   moves  = (const int*)d_in[1];
  const float* values = (const float*)d_in[2];
  const float* W0 = (const float*)d_in[3];
  const float* b0 = (const float*)d_in[4];
  const float* W1 = (const float*)d_in[5];
  const float* b1 = (const float*)d_in[6];
  const float* Wp = (const float*)d_in[7];
  const float* bp = (const float*)d_in[8];
  const float* Wv = (const float*)d_in[9];
  const float* bv = (const float*)d_in[10];
  char* ws = (char*)d_ws;

  __hip_bfloat16* zbuf = (__hip_bfloat16*)(ws + OFF_Z);
  __hip_bfloat16* h1   = (__hip_bfloat16*)(ws + OFF_H1);
  __hip_bfloat16* W0xT = (__hip_bfloat16*)(ws + OFF_W0XT);
  __hip_bfloat16* WpT  = (__hip_bfloat16*)(ws + OFF_WPT);
  float* b0p = (float*)(ws + OFF_B0P);
  float* bpp = (float*)(ws + OFF_BPP);
  float* acc = (float*)(ws + OFF_ACC);

  k_conv_weights<<<956, 256, 0, stream>>>(W0, b0, Wp, bp, ws);
  k_gemm<KP0, true><<<dim3(512, 4), 256, 0, stream>>>(states, W0xT, b0p, zbuf);
  k_scan12<<<32, 1024, 0, stream>>>(zbuf, W0, W1, b1, h1);
  k_heads<<<1024, 256, 0, stream>>>(h1, WpT, bpp, Wv, bv, moves, values, acc);
  k_final<<<1, 1, 0, stream>>>(acc, (float*)d_out);
}

// Round 11
// 899.469 us; speedup vs baseline: 3.1525x; 1.1709x over previous
//
#include <hip/hip_runtime.h>
#include <hip/hip_bf16.h>
#include <stdint.h>

// ---------------------------------------------------------------------------
// RNN_79164837199890: 2-layer LSTM (B=128,T=512,H=128) + policy/value heads.
// R11: R7 numerics/code exactly (R9/R10 "trims" reverted — counter arithmetic
// showed zero VALU reduction + 40% added stall; m240 inline-asm-cvt trap).
// Scan sync rebuilt: NO s_barrier. Producer/consumer wave teams decoupled via
// 4-deep LDS ring buffers + 2 monotone LDS counters (workgroup-scope ds
// atomics, cached in registers, bounded spins). Team0 (8 waves, L0) runs up
// to 3 steps ahead of Team1 (8 waves, L1) -> SIMDs host mixed-phase waves,
// MFMA/VALU/LDS overlap across waves instead of lockstep phase convoys.
// Guards: T0@s: c0>=8s (h0(s-1) ready), c1>=8(s-3) (slot eviction safe).
//         T1@t: c0>=8t (h0(t-1) ready), c1>=8(t-1) (h1(t-2) ready).
// ---------------------------------------------------------------------------

typedef short v8s __attribute__((ext_vector_type(8)));   // 8 x bf16 fragment
typedef float v4f __attribute__((ext_vector_type(4)));   // MFMA accumulator
typedef int   v8i __attribute__((ext_vector_type(8)));   // 32 x fp8 fragment

#define MFMA_B16(a,b,c) __builtin_amdgcn_mfma_f32_16x16x32_bf16((a),(b),(c),0,0,0)
#define MFMA_MX(a,b,c) \
  __builtin_amdgcn_mfma_scale_f32_16x16x128_f8f6f4((a),(b),(c),0,0,0,0x7F7F7F7F,0,0x7F7F7F7F)

#define NT     512
#define FIN    361
#define KP0    384
#define NPC    362
#define NPP    368
#define WGS __HIP_MEMORY_SCOPE_WORKGROUP

// workspace offsets (bytes)
#define OFF_Z    ((size_t)0)          // 65536*512*2 = 67108864 (z0x, gate-packed)
#define OFF_H1   ((size_t)83886080)   // 65536*128*2 = 16777216
#define OFF_W0XT ((size_t)100663296)  // 512*384*2 = 393216
#define OFF_WPT  ((size_t)101187584)  // 368*128*2 = 94208
#define OFF_B0P  ((size_t)101281792)  // 512*4
#define OFF_BPP  ((size_t)101285888)  // 368*4
#define OFF_ACC  ((size_t)101287936)  // 4 floats

static __device__ __forceinline__ short f2b(float f) {
  __hip_bfloat16 h = __float2bfloat16(f);
  union { __hip_bfloat16 h; short s; } cv; cv.h = h; return cv.s;
}
static __device__ __forceinline__ float b2f(unsigned int lo16) {
  union { unsigned u; float f; } cv; cv.u = lo16 << 16; return cv.f;
}
// f32 -> OCP e4m3fn with RNE (one-time weight packs)
static __device__ __forceinline__ unsigned f2e4m3(float f) {
  union { float f; unsigned u; } cv; cv.f = f;
  unsigned s = (cv.u >> 31) << 7;
  float a = fabsf(f);
  a = fminf(a, 448.f);
  unsigned code;
  if (a >= 0.015625f) {
    union { float f; unsigned u; } m; m.f = a;
    unsigned u = m.u + 0x7FFFF + ((m.u >> 20) & 1);
    code = (u >> 20) - 960;
    if (code > 126u) code = 126u;
  } else {
    code = (unsigned)rintf(a * 512.f);
  }
  return s | code;
}
// per-step fp8 encode (R7 path: builtin where available, else manual)
static __device__ __forceinline__ unsigned f2e4m3_fast(float f) {
#if __has_builtin(__builtin_amdgcn_cvt_pk_fp8_f32)
  return (unsigned)__builtin_amdgcn_cvt_pk_fp8_f32(f, f, 0, false) & 0xffu;
#else
  return f2e4m3(f);
#endif
}

// Bounded monotone-counter wait on LDS (workgroup scope; no HBM traffic).
// Returns latest observed value so callers can cache and skip future reads.
static __device__ __forceinline__ int wait_ge(int* f, int tgt, int cached) {
  if (cached >= tgt) return cached;
  int v = 0;
  for (int g = 0; g < (1 << 22); ++g) {
    v = __hip_atomic_load(f, __ATOMIC_ACQUIRE, WGS);
    if (v >= tgt) return v;
    __builtin_amdgcn_s_sleep(1);
  }
  return v;   // bailout: wrong answer, not a hang (diagnosable via absmax)
}

// --------------------------------------------------------------------------
// K0: weight conversion (R7 exact). col' = m*4+g <-> n = m + 128*g;
// forget-gate +1.0 folded into b0p. Zeroes accum.
// --------------------------------------------------------------------------
__global__ __launch_bounds__(256) void k_conv_weights(
    const float* __restrict__ W0, const float* __restrict__ b0,
    const float* __restrict__ Wp, const float* __restrict__ bp,
    char* __restrict__ ws) {
  int idx = blockIdx.x * 256 + threadIdx.x;
  __hip_bfloat16* W0xT = (__hip_bfloat16*)(ws + OFF_W0XT);
  __hip_bfloat16* WpT  = (__hip_bfloat16*)(ws + OFF_WPT);
  float* b0p = (float*)(ws + OFF_B0P);
  float* bpp = (float*)(ws + OFF_BPP);
  float* acc = (float*)(ws + OFF_ACC);

  if (idx < 196608) {                       // W0xT [512 cols'][384 k]
    int np = idx / 384, k = idx - np * 384;
    int n = (np >> 2) + 128 * (np & 3);
    float v = (k < FIN) ? W0[(size_t)k * 512 + n] : 0.f;
    W0xT[idx] = __float2bfloat16(v);
    return;
  }
  idx -= 196608;
  if (idx < 47104) {                        // WpT [368 p][128 k]
    int p = idx >> 7, k = idx & 127;
    WpT[idx] = __float2bfloat16(p < NPC ? Wp[(size_t)k * NPC + p] : 0.f);
    return;
  }
  idx -= 47104;
  if (idx < 512) {                          // b0p packed, +1.0 on forget gate
    int n = (idx >> 2) + 128 * (idx & 3);
    b0p[idx] = b0[n] + (((idx & 3) == 1) ? 1.0f : 0.0f);
    return;
  }
  idx -= 512;
  if (idx < NPP) { bpp[idx] = (idx < NPC) ? bp[idx] : -1e30f; return; }
  idx -= NPP;
  if (idx < 4) { acc[idx] = 0.f; return; }
}

// --------------------------------------------------------------------------
// K1: C[r, col'] = A[r,:] @ BT[col',:]^T + bias[col'] (R7 exact).
// --------------------------------------------------------------------------
template<int KTOT, bool AF32>
__global__ __launch_bounds__(256) void k_gemm(
    const void* __restrict__ Ap, const __hip_bfloat16* __restrict__ BT,
    const float* __restrict__ bias, __hip_bfloat16* __restrict__ C) {
  __shared__ char sm[65536];                 // A: 2x16KB @0, B: 2x16KB @32768
  const int tid = threadIdx.x;
  const int l = tid & 63, wm = tid >> 6;
  const int c = l & 15, lg = l >> 4;
  const int m0 = blockIdx.x * 128;
  const int n0 = blockIdx.y * 128;
  constexpr int NS = KTOT / 64;

  uint4 ra[4], rb[4];
  float fa[32];

  auto LD = [&](int ks) {
#pragma unroll
    for (int i = 0; i < 4; i++) {
      int idx = i * 4096 + tid * 16;
      int row = idx >> 7, colb = idx & 127;
      if constexpr (AF32) {
        int r = m0 + row;
        const float* src = (const float*)Ap + ((size_t)(r & 127) * NT + (r >> 7)) * FIN;
        int kb = ks * 64 + (colb >> 1);
#pragma unroll
        for (int u = 0; u < 8; u++) {
          int kf = kb + u;
          fa[i * 8 + u] = (kf < FIN) ? src[kf] : 0.f;
        }
      } else {
        ra[i] = *(const uint4*)((const char*)Ap + ((size_t)(m0 + row) * KTOT + ks * 64) * 2 + colb);
      }
      rb[i] = *(const uint4*)((const char*)BT + ((size_t)(n0 + row) * KTOT + ks * 64) * 2 + colb);
    }
  };
  auto ST = [&](int bsel) {
#pragma unroll
    for (int i = 0; i < 4; i++) {
      int idx = i * 4096 + tid * 16;
      int row = idx >> 7, colb = idx & 127;
      int sw = colb ^ ((row & 7) << 4);
      if constexpr (AF32) {
        v8s w;
#pragma unroll
        for (int u = 0; u < 8; u++) w[u] = f2b(fa[i * 8 + u]);
        *(v8s*)(sm + bsel * 16384 + row * 128 + sw) = w;
      } else {
        *(uint4*)(sm + bsel * 16384 + row * 128 + sw) = ra[i];
      }
      *(uint4*)(sm + 32768 + bsel * 16384 + row * 128 + sw) = rb[i];
    }
  };

  v4f acc[2][8];
  v4f z4 = {0.f, 0.f, 0.f, 0.f};
#pragma unroll
  for (int mt = 0; mt < 2; mt++)
#pragma unroll
    for (int nt = 0; nt < 8; nt++) acc[mt][nt] = z4;

  LD(0); ST(0);
  __syncthreads();
  for (int ks = 0; ks < NS; ks++) {
    if (ks + 1 < NS) LD(ks + 1);
    const int bsel = ks & 1;
#pragma unroll
    for (int kk = 0; kk < 2; kk++) {
      int bir = kk * 64 + lg * 16;
      v8s af[2];
#pragma unroll
      for (int mt = 0; mt < 2; mt++) {
        int row = wm * 32 + mt * 16 + c;
        af[mt] = *(v8s*)(sm + bsel * 16384 + row * 128 + (bir ^ ((row & 7) << 4)));
      }
#pragma unroll
      for (int nt = 0; nt < 8; nt++) {
        int n = nt * 16 + c;
        v8s bf = *(v8s*)(sm + 32768 + bsel * 16384 + n * 128 + (bir ^ ((n & 7) << 4)));
#pragma unroll
        for (int mt = 0; mt < 2; mt++) acc[mt][nt] = MFMA_B16(af[mt], bf, acc[mt][nt]);
      }
    }
    if (ks + 1 < NS) ST((ks + 1) & 1);
    __syncthreads();
  }

#pragma unroll
  for (int mt = 0; mt < 2; mt++)
#pragma unroll
    for (int nt = 0; nt < 8; nt++) {
      int colp = n0 + nt * 16 + c;
      float bs = bias[colp];
#pragma unroll
      for (int j = 0; j < 4; j++) {
        int row = m0 + wm * 32 + mt * 16 + lg * 4 + j;
        C[(size_t)row * 512 + colp] = __float2bfloat16(acc[mt][nt][j] + bs);
      }
    }
}

// --------------------------------------------------------------------------
// K2: merged 2-layer scan, MX K=128 fp8, DECOUPLED teams (no s_barrier).
// 32 WGs x 16 waves. Team0 = waves 0-7 (L0), Team1 = waves 8-15 (L1).
// lane: m=16rw+c, batch B0+lg (M-row 4lg), 1 cell/lane (R7 geometry).
// LDS: h0 ring 4x2KB @0, h1 ring 4x2KB @8192, counters c0@16384 c1@16448.
// h0(s) -> slot s&3; h1(u) -> slot u&3. 8B-slot XOR swizzle (R7).
// --------------------------------------------------------------------------
__global__ __launch_bounds__(1024, 4) void k_scan12(
    const __hip_bfloat16* __restrict__ Z, const float* __restrict__ W0f,
    const float* __restrict__ W1f, const float* __restrict__ b1,
    __hip_bfloat16* __restrict__ h1out) {
  __shared__ char sm[16512];
  const int tid = threadIdx.x;
  const int l = tid & 63, wv = tid >> 6;
  const int c = l & 15, lg = l >> 4;
  const int role = wv >> 3, rw = wv & 7;
  const int B0 = blockIdx.x * 4;
  const int m_ = 16 * rw + c;
  const int row = 4 * lg;
  const int wf8 = row * 128 + (((m_ >> 3) ^ row) << 3) + (m_ & 7);
  int* c0 = (int*)(sm + 16384);
  int* c1 = (int*)(sm + 16448);

  for (int e = tid * 4; e < 16512; e += 4096) *(int*)(sm + e) = 0;

  auto AFRAG = [&](int base) -> v8i {
    union { unsigned long long q[4]; v8i v; } u;
#pragma unroll
    for (int t = 0; t < 4; t++)
      u.q[t] = *(const unsigned long long*)(
          sm + base + c * 128 + ((((lg * 4 + t) ^ c) & 15) << 3));
    return u.v;
  };

  if (role == 0) {
    // ================= Team0: L0 =================
    v8i breg[4];                             // fp8 W0h B-frags
#pragma unroll
    for (int g = 0; g < 4; g++) {
      int n = g * 128 + m_;
      union { unsigned long long q[4]; v8i v; } u;
#pragma unroll
      for (int t = 0; t < 4; t++) {
        unsigned long long w = 0ull;
#pragma unroll
        for (int j = 0; j < 8; j++) {
          int k = lg * 32 + t * 8 + j;
          w |= (unsigned long long)f2e4m3(W0f[(size_t)(FIN + k) * 512 + n]) << (8 * j);
        }
        u.q[t] = w;
      }
      breg[g] = u.v;
    }

    uint2 zA, zB, zC;
    auto ZLD = [&](int t) -> uint2 {
      return *(const uint2*)(Z + ((size_t)t * 128 + B0 + lg) * 512 + m_ * 4);
    };
    zA = ZLD(0); zB = ZLD(1);
    float cst = 0.f;
    int c0s = 0, c1s = 0;
    __syncthreads();                         // counters/rings zeroed & visible

    for (int s = 0; s < NT; s++) {
      c0s = wait_ge(c0, 8 * s, c0s);                    // h0(s-1) fully written
      if (s >= 4) c1s = wait_ge(c1, 8 * (s - 3), c1s);  // slot s&3 eviction safe
      v8i av = AFRAG(((s + 3) & 3) * 2048);  // h0(s-1) fp8
      v4f acc[4];
#pragma unroll
      for (int g = 0; g < 4; g++) acc[g] = (v4f){0.f, 0.f, 0.f, 0.f};
#pragma unroll
      for (int g = 0; g < 4; g++) acc[g] = MFMA_MX(av, breg[g], acc[g]);
      if (s + 2 < NT) zC = ZLD(s + 2);

      float xi = acc[0][0] + b2f(zA.x & 0xffffu);
      float xf = acc[1][0] + b2f(zA.x >> 16);          // +1.0 folded into b0p
      float xg = acc[2][0] + b2f(zA.y & 0xffffu);
      float xo = acc[3][0] + b2f(zA.y >> 16);
      float ei = __expf(-xi);
      float ef = __expf(-xf);
      float eg = __expf(2.f * xg);
      float eo = __expf(-xo);
      float cn = cst * __builtin_amdgcn_rcpf(1.f + ef)
               + (eg - 1.f) * __builtin_amdgcn_rcpf((1.f + ei) * (eg + 1.f));
      cst = cn;
      float ec = __expf(2.f * cn);
      float hv = (ec - 1.f) * __builtin_amdgcn_rcpf((1.f + eo) * (ec + 1.f));
      *(unsigned char*)(sm + (s & 3) * 2048 + wf8) = (unsigned char)f2e4m3_fast(hv);
      zA = zB; zB = zC;
      asm volatile("s_waitcnt lgkmcnt(0)" ::: "memory");
      if (l == 0) __hip_atomic_fetch_add(c0, 1, __ATOMIC_RELEASE, WGS);
    }
  } else {
    // ================= Team1: L1 =================
    v8i bregH[4], bregX[4];                  // fp8 B-frags
#pragma unroll
    for (int g = 0; g < 4; g++) {
      int n = g * 128 + m_;
      union { unsigned long long q[4]; v8i v; } uh, ux;
#pragma unroll
      for (int t = 0; t < 4; t++) {
        unsigned long long wh = 0ull, wx = 0ull;
#pragma unroll
        for (int j = 0; j < 8; j++) {
          int k = lg * 32 + t * 8 + j;
          wh |= (unsigned long long)f2e4m3(W1f[(size_t)(128 + k) * 512 + n]) << (8 * j);
          wx |= (unsigned long long)f2e4m3(W1f[(size_t)k * 512 + n]) << (8 * j);
        }
        uh.q[t] = wh; ux.q[t] = wx;
      }
      bregH[g] = uh.v; bregX[g] = ux.v;
    }
    float bq[4];
#pragma unroll
    for (int g = 0; g < 4; g++)
      bq[g] = b1[g * 128 + m_] + ((g == 1) ? 1.0f : 0.0f);
    float cst = 0.f;
    int c0s = 0, c1s = 0;
    __syncthreads();

    for (int t = 1; t <= NT; t++) {
      c0s = wait_ge(c0, 8 * t, c0s);         // h0(t-1) ready
      c1s = wait_ge(c1, 8 * (t - 1), c1s);   // h1(t-2) ready (+evict safety)
      v8i ah = AFRAG(8192 + ((t + 2) & 3) * 2048);  // h1(t-2)
      v8i ax = AFRAG(((t + 3) & 3) * 2048);         // h0(t-1)
      v4f acc[4];
#pragma unroll
      for (int g = 0; g < 4; g++) acc[g] = (v4f){bq[g], bq[g], bq[g], bq[g]};
#pragma unroll
      for (int g = 0; g < 4; g++) acc[g] = MFMA_MX(ah, bregH[g], acc[g]);
#pragma unroll
      for (int g = 0; g < 4; g++) acc[g] = MFMA_MX(ax, bregX[g], acc[g]);

      float xi = acc[0][0], xf = acc[1][0], xg = acc[2][0], xo = acc[3][0];
      float ei = __expf(-xi);
      float ef = __expf(-xf);
      float eg = __expf(2.f * xg);
      float eo = __expf(-xo);
      float cn = cst * __builtin_amdgcn_rcpf(1.f + ef)
               + (eg - 1.f) * __builtin_amdgcn_rcpf((1.f + ei) * (eg + 1.f));
      cst = cn;
      float ec = __expf(2.f * cn);
      float hv = (ec - 1.f) * __builtin_amdgcn_rcpf((1.f + eo) * (ec + 1.f));
      *(unsigned char*)(sm + 8192 + ((t - 1) & 3) * 2048 + wf8) =
          (unsigned char)f2e4m3_fast(hv);
      union { short s; __hip_bfloat16 h; } cv; cv.s = f2b(hv);
      h1out[((size_t)(t - 1) * 128 + B0 + lg) * 128 + m_] = cv.h;
      asm volatile("s_waitcnt lgkmcnt(0)" ::: "memory");
      if (l == 0) __hip_atomic_fetch_add(c1, 1, __ATOMIC_RELEASE, WGS);
    }
  }
}

// --------------------------------------------------------------------------
// K5: heads (R7 exact). WG = 64 rows (4 waves x 16).
// --------------------------------------------------------------------------
__global__ __launch_bounds__(256) void k_heads(
    const __hip_bfloat16* __restrict__ Hh, const __hip_bfloat16* __restrict__ WpT,
    const float* __restrict__ bpp, const float* __restrict__ Wv,
    const float* __restrict__ bv, const int* __restrict__ moves,
    const float* __restrict__ values, float* __restrict__ accum) {
  __shared__ char sm[110592];                // A 16KB @0, B 94208B @16384
  const int tid = threadIdx.x;
  const int l = tid & 63, wm = tid >> 6;
  const int c = l & 15, lg = l >> 4;
  const int r0 = blockIdx.x * 64;

#pragma unroll
  for (int i = 0; i < 4; i++) {
    int idx = i * 4096 + tid * 16;
    int row = idx >> 8, colb = idx & 255;
    uint4 v = *(const uint4*)((const char*)Hh + (size_t)r0 * 256 + idx);
    *(uint4*)(sm + row * 256 + (colb ^ ((row & 7) << 4))) = v;
  }
#pragma unroll
  for (int i = 0; i < 23; i++) {
    int idx = i * 4096 + tid * 16;
    int row = idx >> 8, colb = idx & 255;
    uint4 v = *(const uint4*)((const char*)WpT + idx);
    *(uint4*)(sm + 16384 + row * 256 + (colb ^ ((row & 7) << 4))) = v;
  }
  __syncthreads();

  v4f acc[23];
  v4f z4 = {0.f, 0.f, 0.f, 0.f};
#pragma unroll
  for (int q = 0; q < 23; q++) acc[q] = z4;
#pragma unroll
  for (int kk = 0; kk < 4; kk++) {
    int bir = kk * 64 + lg * 16;
    int ar = wm * 16 + c;
    v8s a = *(v8s*)(sm + ar * 256 + (bir ^ ((ar & 7) << 4)));
#pragma unroll
    for (int q = 0; q < 23; q++) {
      int n = q * 16 + c;
      v8s b = *(v8s*)(sm + 16384 + n * 256 + (bir ^ ((n & 7) << 4)));
      acc[q] = MFMA_B16(a, b, acc[q]);
    }
  }
  float bq[23];
#pragma unroll
  for (int q = 0; q < 23; q++) bq[q] = bpp[q * 16 + c];

  float tp = 0.f, tv = 0.f, ta = 0.f, tn = 0.f;
#pragma unroll
  for (int j = 0; j < 4; j++) {
    int rloc = lg * 4 + j;
    int r = r0 + wm * 16 + rloc;
    int t = r >> 7, b = r & 127;
    int mv = moves[(size_t)b * NT + t];
    float val = values[(size_t)b * NT + t];
    float msk = (val != -9.0f) ? 1.f : 0.f;

    float pmax = -3.0e38f;
#pragma unroll
    for (int q = 0; q < 23; q++) pmax = fmaxf(pmax, acc[q][j] + bq[q]);
#pragma unroll
    for (int d = 1; d < 16; d <<= 1) pmax = fmaxf(pmax, __shfl_xor(pmax, d, 64));
    float ps = 0.f;
#pragma unroll
    for (int q = 0; q < 23; q++) ps += __expf((acc[q][j] + bq[q]) - pmax);
#pragma unroll
    for (int d = 1; d < 16; d <<= 1) ps += __shfl_xor(ps, d, 64);
    float lse = pmax + __logf(ps);

    int qm = mv >> 4, cm = mv & 15;
    float mlv = 0.f;
#pragma unroll
    for (int q = 0; q < 23; q++) if (q == qm) mlv = acc[q][j] + bq[q];
    mlv = __shfl(mlv, (l & 48) + cm, 64);
    float xent = lse - mlv;

    float amx = -3.0e38f; int aix = 0;
#pragma unroll
    for (int q = 0; q < 23; q++) {
      float v = acc[q][j] + bq[q];
      if (v > amx) { amx = v; aix = q * 16 + c; }
    }
#pragma unroll
    for (int d = 1; d < 16; d <<= 1) {
      float ov = __shfl_xor(amx, d, 64);
      int oi = __shfl_xor(aix, d, 64);
      if (ov > amx || (ov == amx && oi < aix)) { amx = ov; aix = oi; }
    }

    float pd = 0.f;
    int vrow = wm * 16 + rloc;
#pragma unroll
    for (int i = 0; i < 8; i++) {
      int k = c * 8 + i;
      short hv = *(short*)(sm + vrow * 256 + ((k * 2) ^ ((vrow & 7) << 4)));
      pd += b2f((unsigned short)hv) * Wv[k];
    }
#pragma unroll
    for (int d = 1; d < 16; d <<= 1) pd += __shfl_xor(pd, d, 64);
    float eo = __expf(2.f * (pd + bv[0]));
    float win = (eo - 1.f) * __builtin_amdgcn_rcpf(eo + 1.f);
    float dv = win - val;

    if (c == 0) {
      tp += msk * xent;
      tv += msk * dv * dv;
      ta += (aix == mv) ? 1.f : 0.f;
      tn += msk;
    }
  }
  tp += __shfl_xor(tp, 16, 64); tp += __shfl_xor(tp, 32, 64);
  tv += __shfl_xor(tv, 16, 64); tv += __shfl_xor(tv, 32, 64);
  ta += __shfl_xor(ta, 16, 64); ta += __shfl_xor(ta, 32, 64);
  tn += __shfl_xor(tn, 16, 64); tn += __shfl_xor(tn, 32, 64);
  if (l == 0) {
    atomicAdd(accum + 0, tp);
    atomicAdd(accum + 1, tv);
    atomicAdd(accum + 2, ta);
    atomicAdd(accum + 3, tn);
  }
}

__global__ void k_final(const float* __restrict__ accum, float* __restrict__ out) {
  if (threadIdx.x == 0) {
    float nm = accum[3];
    out[0] = accum[0] / nm;
    out[1] = accum[1] / nm;
    out[2] = accum[2] / 65536.0f;
  }
}

// --------------------------------------------------------------------------
extern "C" void kernel_launch(void* const* d_in, const int* in_sizes, int n_in,
                              void* d_out, int out_size, void* d_ws, size_t ws_size,
                              hipStream_t stream) {
  (void)in_sizes; (void)n_in; (void)out_size; (void)ws_size;
  const float* states = (const float*)d_in[0];
  const int*   moves  = (const int*)d_in[1];
  const float* values = (const float*)d_in[2];
  const float* W0 = (const float*)d_in[3];
  const float* b0 = (const float*)d_in[4];
  const float* W1 = (const float*)d_in[5];
  const float* b1 = (const float*)d_in[6];
  const float* Wp = (const float*)d_in[7];
  const float* bp = (const float*)d_in[8];
  const float* Wv = (const float*)d_in[9];
  const float* bv = (const float*)d_in[10];
  char* ws = (char*)d_ws;

  __hip_bfloat16* zbuf = (__hip_bfloat16*)(ws + OFF_Z);
  __hip_bfloat16* h1   = (__hip_bfloat16*)(ws + OFF_H1);
  __hip_bfloat16* W0xT = (__hip_bfloat16*)(ws + OFF_W0XT);
  __hip_bfloat16* WpT  = (__hip_bfloat16*)(ws + OFF_WPT);
  float* b0p = (float*)(ws + OFF_B0P);
  float* bpp = (float*)(ws + OFF_BPP);
  float* acc = (float*)(ws + OFF_ACC);

  k_conv_weights<<<956, 256, 0, stream>>>(W0, b0, Wp, bp, ws);
  k_gemm<KP0, true><<<dim3(512, 4), 256, 0, stream>>>(states, W0xT, b0p, zbuf);
  k_scan12<<<32, 1024, 0, stream>>>(zbuf, W0, W1, b1, h1);
  k_heads<<<1024, 256, 0, stream>>>(h1, WpT, bpp, Wv, bv, moves, values, acc);
  k_final<<<1, 1, 0, stream>>>(acc, (float*)d_out);
}